// Round 7
// baseline (1274.962 us; speedup 1.0000x reference)
//
#include <hip/hip_runtime.h>
#include <hip/hip_bf16.h>
#include <math.h>

// Problem constants (reference: B,T,D=64, E=HA=HB=128, OUT=1, short=2)
#define B_ 64
#define T_ 64
#define D_ 64
#define PMIN 3        // short+1
#define NPOUT 60      // T-2-short
#define NCHUNK 4      // batch chunks of 16 per prefix (2 chunks per WG)

typedef __hip_bfloat16 bf16;
typedef __attribute__((ext_vector_type(4))) short s16x4;
typedef __attribute__((ext_vector_type(8))) short s16x8;
typedef __attribute__((ext_vector_type(4))) float f32x4;

// ---- canonical fp32 input copies (element offsets within OFF_IN) ----
#define CI_X      0
#define CI_WEMB   262144
#define CI_BEMB   270336
#define CI_WIA    270464
#define CI_WHA    319616
#define CI_BIA    368768
#define CI_BHA    369152
#define CI_WIB    369536
#define CI_WHB    418688
#define CI_BIB    467840
#define CI_BHB    468224
#define CI_WA     468608
#define CI_BA     468736
#define CI_WB     468737
#define CI_BB     485121
#define CI_WO     485249
#define CI_BO     485377
#define CI_TOTAL  485378

// ---- workspace layout (fp32 element offsets; all packs 16B-aligned) ----
#define OFF_EMB   0                      // [t][b][128] fp32
#define OFF_WIC   524288                 // WicT [e][768] fp32
#define OFF_XT    622592                 // xt [t][d][b] fp32
#define OFF_IN    884736                 // canonical fp32 inputs
#define OFF_GIPK  1370116                // bf16 [t][chunk4][w][lane][24]
#define OFF_WPK   2942980                // bf16 [w][nt6][kt][lane][8] (pi-k)
#define OFF_BPPK  2992132                // bf16 [w8][kt][lane][8]     (pi-k)
#define OFF_WMPK  3000324                // bf16 [nt4][kt][lane][8]    (true e)
#define OFF_WALPK 3004420                // bf16 [kt][lane][8]         (pi-k)
#define OFF_FLAG  3005444

__device__ __forceinline__ float bf2f(unsigned short u) {
    union { float f; unsigned u32; } x; x.u32 = ((unsigned)u) << 16; return x.f;
}
__device__ __forceinline__ unsigned short f2bf(float f) {
    union { float f; unsigned u; } x; x.f = f;
    unsigned r = x.u + 0x7FFFu + ((x.u >> 16) & 1u);
    return (unsigned short)(r >> 16);
}
__device__ __forceinline__ float sigmoidf_(float v) { return 1.f / (1.f + __expf(-v)); }
__device__ __forceinline__ float tanhf_(float v) {
    float e = __expf(-2.f * fabsf(v));
    float t = (1.f - e) / (1.f + e);
    return copysignf(t, v);
}
// k-dimension permutation: stored slot s -> true index (pairs (l,t) adjacent)
__device__ __forceinline__ int kpi(int s) {
    return (s & ~31) | ((s & 1) << 4) | ((s & 31) >> 1);
}
__device__ __forceinline__ s16x8 ldA(const short* p) {   // 8B-aligned 16-byte LDS read
    s16x4 lo = *(const s16x4*)p;
    s16x4 hi = *(const s16x4*)(p + 4);
    return __builtin_shufflevector(lo, hi, 0, 1, 2, 3, 4, 5, 6, 7);
}

// ---------------- dtype detection ----------------
__global__ void detect_dtype(const unsigned short* xr, int* flag)
{
    int tid = threadIdx.x;
    int bad = 0;
    for (int i = tid; i < 4096; i += 256) {
        int ex = (xr[i] >> 7) & 0xFF;
        if (ex >= 140) bad++;
    }
    __shared__ int s[256];
    s[tid] = bad;
    __syncthreads();
    for (int st = 128; st > 0; st >>= 1) {
        if (tid < st) s[tid] += s[tid + st];
        __syncthreads();
    }
    if (tid == 0) *flag = (s[0] > 4) ? 1 : 0;
}

// ---------------- canonicalize inputs (block-uniform tensor select) ----------------
__global__ void convert_inputs(const void* p0, const void* p1, const void* p2,
                               const void* p3, const void* p4, const void* p5,
                               const void* p6, const void* p7, const void* p8,
                               const void* p9, const void* p10, const void* p11,
                               const void* p12, const void* p13, const void* p14,
                               const void* p15, const void* p16,
                               float* ws, const int* flagp)
{
    const int bc[17]     = {1024, 32, 1, 192, 192, 2, 2, 192, 192, 2, 2, 1, 1, 64, 1, 1, 1};
    const int sizes[17]  = {262144, 8192, 128, 49152, 49152, 384, 384, 49152, 49152,
                            384, 384, 128, 1, 16384, 128, 128, 1};
    const int starts[17] = {CI_X, CI_WEMB, CI_BEMB, CI_WIA, CI_WHA, CI_BIA, CI_BHA,
                            CI_WIB, CI_WHB, CI_BIB, CI_BHB, CI_WA, CI_BA, CI_WB,
                            CI_BB, CI_WO, CI_BO};
    int b = blockIdx.x, k = 0;
    while (b >= bc[k]) { b -= bc[k]; k++; }
    int li = b * 256 + threadIdx.x;
    if (li >= sizes[k]) return;
    const void* p;
    switch (k) {
        case 0: p = p0; break;  case 1: p = p1; break;  case 2: p = p2; break;
        case 3: p = p3; break;  case 4: p = p4; break;  case 5: p = p5; break;
        case 6: p = p6; break;  case 7: p = p7; break;  case 8: p = p8; break;
        case 9: p = p9; break;  case 10: p = p10; break; case 11: p = p11; break;
        case 12: p = p12; break; case 13: p = p13; break; case 14: p = p14; break;
        case 15: p = p15; break; default: p = p16; break;
    }
    float v;
    if (*flagp) v = ((const float*)p)[li];
    else        v = bf2f(((const unsigned short*)p)[li]);
    ws[OFF_IN + starts[k] + li] = v;
}

// ---------------- prep_all: WicT + emb + xt + all weight packs ----------------
__global__ void prep_all(float* ws)
{
    const float* cin = ws + OFF_IN;
    int id = blockIdx.x * 256 + threadIdx.x;
    if (id < 98304) {                                 // WicT [e][768]
        int e = id / 768, g = id % 768;
        float v = (g < 384) ? cin[CI_WIA + g * 128 + e]
                            : cin[CI_WIB + (g - 384) * 128 + e];
        ws[OFF_WIC + id] = v;
    } else if (id < 622592) {                         // emb [t][b][128]
        int id2 = id - 98304;
        int e = id2 & 127;
        int tb = id2 >> 7;
        int b = tb & 63, t = tb >> 6;
        const float* xp = cin + CI_X + (b * T_ + t) * D_;
        const float* wp = cin + CI_WEMB + e * D_;
        float acc = cin[CI_BEMB + e];
        #pragma unroll
        for (int d = 0; d < 64; d += 4) {
            f32x4 xv = *(const f32x4*)(xp + d);
            f32x4 wv = *(const f32x4*)(wp + d);
            acc += xv[0]*wv[0] + xv[1]*wv[1] + xv[2]*wv[2] + xv[3]*wv[3];
        }
        ws[OFF_EMB + id2] = acc;
    } else if (id < 884736) {                         // xt [t][d][b]
        int id5 = id - 622592;
        int b = id5 & 63, d = (id5 >> 6) & 63, t = id5 >> 12;
        ws[OFF_XT + id5] = cin[CI_X + (b * 64 + t) * 64 + d];
    } else if (id < 983040) {                         // gh weights (pi-k)
        unsigned short* wpk = (unsigned short*)(ws + OFF_WPK);
        int id3 = id - 884736;
        int w = id3 / 12288, r1 = id3 % 12288;
        int nt = r1 / 2048, r2 = r1 % 2048;
        int kt = r2 / 512, r3 = r2 % 512;
        int lane = r3 >> 3, j = r3 & 7;
        int cell = w >> 2, wv = w & 3;
        int gate = nt >> 1, tt = nt & 1;
        int g = gate * 128 + wv * 32 + tt * 16 + (lane & 15);
        int k = kpi(kt * 32 + (lane >> 4) * 8 + j);
        wpk[id3] = f2bf(cin[(cell ? CI_WHB : CI_WHA) + g * 128 + k]);
    } else if (id < 999424) {                         // Wb (pi-k)
        unsigned short* bpk = (unsigned short*)(ws + OFF_BPPK);
        int id4 = id - 983040;
        int w = id4 / 2048, r = id4 % 2048;
        int kt = r / 512, lane = (r % 512) >> 3, j = r & 7;
        int e = w * 16 + (lane & 15);
        int k = kpi(kt * 32 + (lane >> 4) * 8 + j);
        bpk[id4] = f2bf(cin[CI_WB + e * 128 + k]);
    } else if (id < 1007616) {                        // Wm (true e)
        unsigned short* wmk = (unsigned short*)(ws + OFF_WMPK);
        int id6 = id - 999424;
        int nt = id6 / 2048, r = id6 % 2048;
        int kt = r / 512, lane = (r % 512) >> 3, j = r & 7;
        int d = nt * 16 + (lane & 15);
        int e = kt * 32 + (lane >> 4) * 8 + j;
        wmk[id6] = f2bf(cin[CI_WO + e] * cin[CI_WEMB + e * 64 + d]);
    } else {                                          // Wa alpha tile (pi-k)
        unsigned short* alk = (unsigned short*)(ws + OFF_WALPK);
        int id7 = id - 1007616;
        int kt = id7 / 512, lane = (id7 % 512) >> 3, j = id7 & 7;
        int k = kpi(kt * 32 + (lane >> 4) * 8 + j);
        alk[id7] = ((lane & 15) == 0) ? f2bf(cin[CI_WA + k]) : (unsigned short)0;
    }
}

// ---------------- prep_gi: LDS-staged scatter, coalesced dwordx4 dump ----------------
__global__ void prep_gi(float* ws)
{
    const float* cin = ws + OFF_IN;
    unsigned short* gipk = (unsigned short*)(ws + OFF_GIPK);
    int t = blockIdx.x >> 2;
    int chunk = blockIdx.x & 3;
    int b0 = chunk * 16;
    int tid = threadIdx.x;
    __shared__ __align__(16) float semT[128][16];
    __shared__ __align__(16) unsigned short stg[12288];   // block's gipk span
    #pragma unroll
    for (int q = 0; q < 8; q++) {
        int idx = tid + q * 256;
        int r = idx & 15, e = idx >> 4;
        semT[e][r] = ws[OFF_EMB + (size_t)((t * 64 + b0 + r) * 128) + e];
    }
    __syncthreads();
    float acc[3][16];
    #pragma unroll
    for (int g3 = 0; g3 < 3; g3++)
        #pragma unroll
        for (int r = 0; r < 16; r++) acc[g3][r] = 0.f;
    const float* wic = ws + OFF_WIC;
    for (int e = 0; e < 128; e++) {
        f32x4 h0 = *(const f32x4*)&semT[e][0];
        f32x4 h1 = *(const f32x4*)&semT[e][4];
        f32x4 h2 = *(const f32x4*)&semT[e][8];
        f32x4 h3 = *(const f32x4*)&semT[e][12];
        float hv[16] = {h0[0],h0[1],h0[2],h0[3], h1[0],h1[1],h1[2],h1[3],
                        h2[0],h2[1],h2[2],h2[3], h3[0],h3[1],h3[2],h3[3]};
        float w0 = wic[e * 768 + tid];
        float w1 = wic[e * 768 + tid + 256];
        float w2 = wic[e * 768 + tid + 512];
        #pragma unroll
        for (int r = 0; r < 16; r++) {
            acc[0][r] += hv[r] * w0;
            acc[1][r] += hv[r] * w1;
            acc[2][r] += hv[r] * w2;
        }
    }
    #pragma unroll
    for (int g3 = 0; g3 < 3; g3++) {
        int g = tid + g3 * 256;
        int cellg = g / 384, gr = g % 384;
        int gate = gr / 128, kh = gr % 128;
        int wvp = kh / 32, tt2 = (kh % 32) / 16, l15p = kh % 16;
        int wq = cellg * 4 + wvp;
        float bias = cin[(cellg ? CI_BIB : CI_BIA) + gr];
        if (gate < 2) bias += cin[(cellg ? CI_BHB : CI_BHA) + gr];
        #pragma unroll
        for (int r = 0; r < 16; r++) {
            float v = acc[g3][r] + bias;
            int lane2 = (r >> 2) * 16 + l15p;
            int slot = gate * 8 + tt2 * 4 + (r & 3);
            stg[(wq * 64 + lane2) * 24 + slot] = f2bf(v);
        }
    }
    __syncthreads();
    const uint4* s4 = (const uint4*)stg;                  // 1536 uint4
    uint4* d4 = (uint4*)(gipk + (size_t)(t * 4 + chunk) * 12288);
    #pragma unroll
    for (int i = 0; i < 6; i++) d4[tid + i * 256] = s4[tid + i * 256];
}

// ---------------- fused chain kernel ----------------
// 120 WGs: (prefix p, chunk-pair). 1024 threads = 16 waves = TWO independent
// 16-row chunk chains of the SAME prefix (lockstep, shared barrier) -> 4
// waves/SIMD to hide latency with zero wasted MFMA/VALU work.
// Within a half: wave w = cell*4+wv: 6 gate n-tiles + betapre; w==7 alpha.

__launch_bounds__(1024, 4)
__global__ void chain_kernel(const float* ws, void* outv, const int* flagp,
                             const void* p_bha, const void* p_bhb,
                             const void* p_bb, const void* p_ba,
                             const void* p_bo, const void* p_wo)
{
    const int p = PMIN + (int)blockIdx.x / 2;
    const int pair = (int)blockIdx.x & 1;
    const int tid = threadIdx.x;
    const int lane = tid & 63;
    const int W = tid >> 6;          // 0..15
    const int half = W >> 3;
    const int w = W & 7;
    const int chunk = pair * 2 + half;
    const int cell = w >> 2;
    const int wv = w & 3;
    const int l15 = lane & 15;
    const int quad = lane >> 4;

    __shared__ __align__(16) short hbf[2][2][2][16][132];  // [half][buf][cell][row][m]
    __shared__ __align__(16) short betbf[2][2][16][132];   // [half][buf][row][e]
    __shared__ __align__(16) short sWm[4][4][64][8];
    __shared__ float spaLds[2][2][16];

    const unsigned short* gipk = (const unsigned short*)(ws + OFF_GIPK);
    const unsigned short* wpk  = (const unsigned short*)(ws + OFF_WPK);
    const unsigned short* bpk  = (const unsigned short*)(ws + OFF_BPPK);
    const unsigned short* alk  = (const unsigned short*)(ws + OFF_WALPK);
    const int flag = *flagp;

    {   // stage Wm; zero all h buffers
        const int* s2 = (const int*)(ws + OFF_WMPK);
        int* d2 = (int*)&sWm[0][0][0][0];
        for (int i = tid; i < 4096; i += 1024) d2[i] = s2[i];
        int* hz = (int*)&hbf[0][0][0][0][0];
        for (int i = tid; i < 8448; i += 1024) hz[i] = 0;
    }

    // persistent B-fragment registers (same for both halves)
    s16x8 wB[6][4];
    #pragma unroll
    for (int nt = 0; nt < 6; nt++)
        #pragma unroll
        for (int kt = 0; kt < 4; kt++)
            wB[nt][kt] = *(const s16x8*)(wpk + (((w * 6 + nt) * 4 + kt) * 64 + lane) * 8);
    s16x8 bBp[4], wAl[4];
    #pragma unroll
    for (int kt = 0; kt < 4; kt++) {
        bBp[kt] = *(const s16x8*)(bpk + ((w * 4 + kt) * 64 + lane) * 8);
        wAl[kt] = *(const s16x8*)(alk + (kt * 64 + lane) * 8);
    }

    // per-lane constants
    float bhn0, bhn1, bbE, baf, bof;
    if (flag) {
        const float* bh = (const float*)(cell ? p_bhb : p_bha);
        bhn0 = bh[256 + wv * 32 + l15];
        bhn1 = bh[256 + wv * 32 + 16 + l15];
        bbE = ((const float*)p_bb)[w * 16 + l15];
        baf = ((const float*)p_ba)[0];
        bof = ((const float*)p_bo)[0];
    } else {
        const unsigned short* bh = (const unsigned short*)(cell ? p_bhb : p_bha);
        bhn0 = bf2f(bh[256 + wv * 32 + l15]);
        bhn1 = bf2f(bh[256 + wv * 32 + 16 + l15]);
        bbE = bf2f(((const unsigned short*)p_bb)[w * 16 + l15]);
        baf = bf2f(((const unsigned short*)p_ba)[0]);
        bof = bf2f(((const unsigned short*)p_bo)[0]);
    }

    float h_old[8];
    #pragma unroll
    for (int i = 0; i < 8; i++) h_old[i] = 0.f;
    float gAccR[4] = {0.f, 0.f, 0.f, 0.f};   // waves w 0-3
    float cAccR[8] = {0.f, 0.f, 0.f, 0.f, 0.f, 0.f, 0.f, 0.f};  // waves w 4-7
    float sl4[4] = {0.f, 0.f, 0.f, 0.f};
    float slB = 0.f;

    s16x8 giv[3], givN[3];
    {
        const unsigned short* gp =
            gipk + ((((size_t)p * 4 + chunk) * 8 + w) * 64 + lane) * 24;
        #pragma unroll
        for (int i = 0; i < 3; i++) giv[i] = *(const s16x8*)(gp + i * 8);
    }

    __syncthreads();

    for (int it = 0; it <= p + 1; it++) {
        const int j = p - it;
        const int jp = j + 1;
        const bool doGru = (j >= 0);
        const bool doAcc = (it > 0);
        const int cur = it & 1;
        const int nxt = cur ^ 1;
        const int dbuf = it & 1;

        // prefetch next gi
        if (j > 0) {
            const unsigned short* gp =
                gipk + ((((size_t)(j - 1) * 4 + chunk) * 8 + w) * 64 + lane) * 24;
            #pragma unroll
            for (int i = 0; i < 3; i++) givN[i] = *(const s16x8*)(gp + i * 8);
        }
        // prefetch x / emb for Phase C
        f32x4 xv, em0, em1;
        if (doAcc) {
            if (w < 4) {
                xv = *(const f32x4*)(ws + OFF_XT + ((size_t)jp * 64 + w * 16 + l15) * 64
                                     + chunk * 16 + quad * 4);
            } else {
                const int row = quad * 4 + (w - 4);
                const float* ep = ws + OFF_EMB
                                  + ((size_t)jp * 64 + chunk * 16 + row) * 128 + l15 * 8;
                em0 = *(const f32x4*)ep;
                em1 = *(const f32x4*)(ep + 4);
            }
        }

        // ---- Phase A: MFMA gates + betapre (+ alpha on w==7) ----
        f32x4 Cg[6], Cbp, Cal;
        #pragma unroll
        for (int nt = 0; nt < 6; nt++) Cg[nt] = (f32x4){0.f,0.f,0.f,0.f};
        Cbp = (f32x4){0.f,0.f,0.f,0.f};
        Cal = (f32x4){0.f,0.f,0.f,0.f};

        #pragma unroll
        for (int kt = 0; kt < 4; kt++) {
            s16x8 aA = ldA(&hbf[half][cur][0][l15][kt * 32 + quad * 8]);
            s16x8 aB = ldA(&hbf[half][cur][1][l15][kt * 32 + quad * 8]);
            s16x8 aOwn = cell ? aB : aA;
            #pragma unroll
            for (int nt = 0; nt < 6; nt++)
                Cg[nt] = __builtin_amdgcn_mfma_f32_16x16x32_bf16(aOwn, wB[nt][kt], Cg[nt], 0, 0, 0);
            Cbp = __builtin_amdgcn_mfma_f32_16x16x32_bf16(aB, bBp[kt], Cbp, 0, 0, 0);
            if (w == 7)
                Cal = __builtin_amdgcn_mfma_f32_16x16x32_bf16(aA, wAl[kt], Cal, 0, 0, 0);
        }

        // ---- Phase B ----
        if (w == 7 && l15 == 0) {
            #pragma unroll
            for (int reg = 0; reg < 4; reg++)
                spaLds[half][dbuf][quad * 4 + reg] = fminf(0.5f * Cal[reg] + baf, 60.f);
        }
        if (doGru) {
            #pragma unroll
            for (int reg = 0; reg < 4; reg++) {
                float hn2[2];
                #pragma unroll
                for (int tt = 0; tt < 2; tt++) {
                    float gir = bf2f((unsigned short)giv[0][tt * 4 + reg]);
                    float giz = bf2f((unsigned short)giv[1][tt * 4 + reg]);
                    float gin = bf2f((unsigned short)giv[2][tt * 4 + reg]);
                    float ghr = Cg[0 + tt][reg];
                    float ghz = Cg[2 + tt][reg];
                    float ghn = Cg[4 + tt][reg] + (tt ? bhn1 : bhn0);
                    float ho  = h_old[tt * 4 + reg];
                    float rr = sigmoidf_(gir + ghr);
                    float zz = sigmoidf_(giz + ghz);
                    float nn = tanhf_(gin + rr * ghn);
                    float hv2 = (1.f - zz) * nn + zz * ho;
                    h_old[tt * 4 + reg] = hv2;
                    hn2[tt] = hv2;
                }
                unsigned pk = (unsigned)f2bf(hn2[0]) | ((unsigned)f2bf(hn2[1]) << 16);
                *(unsigned*)&hbf[half][nxt][cell][quad * 4 + reg][wv * 32 + l15 * 2] = pk;
            }
        }
        #pragma unroll
        for (int reg = 0; reg < 4; reg++) {
            float bv = tanhf_(0.5f * Cbp[reg] + bbE);
            betbf[half][dbuf][quad * 4 + reg][w * 16 + l15] = (short)f2bf(bv);
        }

        __syncthreads();   // the ONE barrier

        // ---- Phase C: attention accumulation (scan step it-1) ----
        if (doAcc) {
            if (w < 4) {
                f32x4 ec = (f32x4){0.f,0.f,0.f,0.f};
                #pragma unroll
                for (int kt = 0; kt < 4; kt++) {
                    s16x8 a = ldA(&betbf[half][dbuf][l15][kt * 32 + quad * 8]);
                    s16x8 bw = *(const s16x8*)&sWm[w][kt][lane][0];
                    ec = __builtin_amdgcn_mfma_f32_16x16x32_bf16(a, bw, ec, 0, 0, 0);
                }
                #pragma unroll
                for (int reg = 0; reg < 4; reg++) {
                    float we = __expf(spaLds[half][dbuf][quad * 4 + reg]);
                    sl4[reg] += we;
                    gAccR[reg] += we * ec[reg] * xv[reg];
                }
            } else {
                const int row = quad * 4 + (w - 4);
                float we = __expf(spaLds[half][dbuf][row]);
                slB += we;
                const short* bp2 = &betbf[half][dbuf][row][l15 * 8];
                s16x4 blo = *(const s16x4*)bp2;
                s16x4 bhi = *(const s16x4*)(bp2 + 4);
                #pragma unroll
                for (int v = 0; v < 4; v++)
                    cAccR[v] += we * bf2f((unsigned short)blo[v]) * em0[v];
                #pragma unroll
                for (int v = 0; v < 4; v++)
                    cAccR[4 + v] += we * bf2f((unsigned short)bhi[v]) * em1[v];
            }
        }

        if (j > 0) { giv[0] = givN[0]; giv[1] = givN[1]; giv[2] = givN[2]; }
    }

    // ---- epilogue ----
    if (w >= 4) {       // pred = (c . Wo)/sl + bo
        const int row = quad * 4 + (w - 4);
        float wo8[8];
        if (flag) {
            const float* wp = (const float*)p_wo + l15 * 8;
            #pragma unroll
            for (int v = 0; v < 8; v++) wo8[v] = wp[v];
        } else {
            const unsigned short* wp = (const unsigned short*)p_wo + l15 * 8;
            #pragma unroll
            for (int v = 0; v < 8; v++) wo8[v] = bf2f(wp[v]);
        }
        float part = 0.f;
        #pragma unroll
        for (int v = 0; v < 8; v++) part += cAccR[v] * wo8[v];
        part += __shfl_xor(part, 1);
        part += __shfl_xor(part, 2);
        part += __shfl_xor(part, 4);
        part += __shfl_xor(part, 8);
        if (l15 == 0) {
            int bglob = chunk * 16 + row;
            float pr = part / slB + bof;
            size_t oi = (size_t)bglob * NPOUT + (p - PMIN);
            if (flag) ((float*)outv)[oi] = pr;
            else      ((bf16*)outv)[oi] = __float2bfloat16(pr);
        }
    } else {            // weight = g/sl/(p+1)
        const float invt = 1.f / (float)(p + 1);
        #pragma unroll
        for (int reg = 0; reg < 4; reg++) {
            int row = quad * 4 + reg;
            int bglob = chunk * 16 + row;
            float gv = gAccR[reg] / sl4[reg] * invt;
            size_t oi = (size_t)B_ * NPOUT
                      + ((size_t)bglob * NPOUT + (p - PMIN)) * 64 + w * 16 + l15;
            if (flag) ((float*)outv)[oi] = gv;
            else      ((bf16*)outv)[oi] = __float2bfloat16(gv);
        }
    }
}

// ---------------- launch ----------------
extern "C" void kernel_launch(void* const* d_in, const int* in_sizes, int n_in,
                              void* d_out, int out_size, void* d_ws, size_t ws_size,
                              hipStream_t stream)
{
    float* ws = (float*)d_ws;
    int* flagp = (int*)(ws + OFF_FLAG);

    hipLaunchKernelGGL(detect_dtype, dim3(1), dim3(256), 0, stream,
                       (const unsigned short*)d_in[0], flagp);
    hipLaunchKernelGGL(convert_inputs, dim3(1902), dim3(256), 0, stream,
                       d_in[0], d_in[1], d_in[2], d_in[3], d_in[4], d_in[5],
                       d_in[6], d_in[7], d_in[8], d_in[9], d_in[10], d_in[11],
                       d_in[12], d_in[13], d_in[14], d_in[15], d_in[16],
                       ws, flagp);
    hipLaunchKernelGGL(prep_all, dim3(3944), dim3(256), 0, stream, ws);
    hipLaunchKernelGGL(prep_gi,  dim3(256),  dim3(256), 0, stream, ws);
    hipLaunchKernelGGL(chain_kernel, dim3(NPOUT * 2), dim3(1024), 0, stream,
                       ws, d_out, flagp,
                       d_in[6], d_in[10], d_in[14], d_in[12], d_in[16], d_in[15]);
}

// Round 8
// 750.537 us; speedup vs baseline: 1.6987x; 1.6987x over previous
//
#include <hip/hip_runtime.h>
#include <hip/hip_bf16.h>
#include <math.h>

// Problem constants (reference: B,T,D=64, E=HA=HB=128, OUT=1, short=2)
#define B_ 64
#define T_ 64
#define D_ 64
#define PMIN 3        // short+1
#define NPOUT 60      // T-2-short
#define NCHUNK 4      // batch chunks of 16 per prefix (2 chunks per WG)

typedef __hip_bfloat16 bf16;
typedef __attribute__((ext_vector_type(4))) short s16x4;
typedef __attribute__((ext_vector_type(8))) short s16x8;
typedef __attribute__((ext_vector_type(4))) float f32x4;

// ---- canonical fp32 input copies (element offsets within OFF_IN) ----
#define CI_X      0
#define CI_WEMB   262144
#define CI_BEMB   270336
#define CI_WIA    270464
#define CI_WHA    319616
#define CI_BIA    368768
#define CI_BHA    369152
#define CI_WIB    369536
#define CI_WHB    418688
#define CI_BIB    467840
#define CI_BHB    468224
#define CI_WA     468608
#define CI_BA     468736
#define CI_WB     468737
#define CI_BB     485121
#define CI_WO     485249
#define CI_BO     485377
#define CI_TOTAL  485378

// ---- workspace layout (fp32 element offsets; all packs 16B-aligned) ----
#define OFF_EMB   0                      // [t][b][128] fp32
#define OFF_WIC   524288                 // WicT [e][768] fp32
#define OFF_XT    622592                 // xt [t][d][b] fp32
#define OFF_IN    884736                 // canonical fp32 inputs
#define OFF_GIPK  1370116                // bf16 [t][chunk4][w][lane][24]
#define OFF_WPK   2942980                // bf16 [w][nt6][kt][lane][8] (pi-k)
#define OFF_BPPK  2992132                // bf16 [w8][kt][lane][8]     (pi-k)
#define OFF_WMPK  3000324                // bf16 [nt4][kt][lane][8]    (true e)
#define OFF_WALPK 3004420                // bf16 [kt][lane][8]         (pi-k)
#define OFF_FLAG  3005444

__device__ __forceinline__ float bf2f(unsigned short u) {
    union { float f; unsigned u32; } x; x.u32 = ((unsigned)u) << 16; return x.f;
}
__device__ __forceinline__ unsigned short f2bf(float f) {
    union { float f; unsigned u; } x; x.f = f;
    unsigned r = x.u + 0x7FFFu + ((x.u >> 16) & 1u);
    return (unsigned short)(r >> 16);
}
__device__ __forceinline__ float sigmoidf_(float v) { return 1.f / (1.f + __expf(-v)); }
__device__ __forceinline__ float tanhf_(float v) {
    float e = __expf(-2.f * fabsf(v));
    float t = (1.f - e) / (1.f + e);
    return copysignf(t, v);
}
// k-dimension permutation: stored slot s -> true index (pairs (l,t) adjacent)
__device__ __forceinline__ int kpi(int s) {
    return (s & ~31) | ((s & 1) << 4) | ((s & 31) >> 1);
}
__device__ __forceinline__ s16x8 ldA(const short* p) {   // 8B-aligned 16-byte LDS read
    s16x4 lo = *(const s16x4*)p;
    s16x4 hi = *(const s16x4*)(p + 4);
    return __builtin_shufflevector(lo, hi, 0, 1, 2, 3, 4, 5, 6, 7);
}

// ---------------- dtype detection ----------------
__global__ void detect_dtype(const unsigned short* xr, int* flag)
{
    int tid = threadIdx.x;
    int bad = 0;
    for (int i = tid; i < 4096; i += 256) {
        int ex = (xr[i] >> 7) & 0xFF;
        if (ex >= 140) bad++;
    }
    __shared__ int s[256];
    s[tid] = bad;
    __syncthreads();
    for (int st = 128; st > 0; st >>= 1) {
        if (tid < st) s[tid] += s[tid + st];
        __syncthreads();
    }
    if (tid == 0) *flag = (s[0] > 4) ? 1 : 0;
}

// ---------------- canonicalize inputs (block-uniform tensor select) ----------------
__global__ void convert_inputs(const void* p0, const void* p1, const void* p2,
                               const void* p3, const void* p4, const void* p5,
                               const void* p6, const void* p7, const void* p8,
                               const void* p9, const void* p10, const void* p11,
                               const void* p12, const void* p13, const void* p14,
                               const void* p15, const void* p16,
                               float* ws, const int* flagp)
{
    const int bc[17]     = {1024, 32, 1, 192, 192, 2, 2, 192, 192, 2, 2, 1, 1, 64, 1, 1, 1};
    const int sizes[17]  = {262144, 8192, 128, 49152, 49152, 384, 384, 49152, 49152,
                            384, 384, 128, 1, 16384, 128, 128, 1};
    const int starts[17] = {CI_X, CI_WEMB, CI_BEMB, CI_WIA, CI_WHA, CI_BIA, CI_BHA,
                            CI_WIB, CI_WHB, CI_BIB, CI_BHB, CI_WA, CI_BA, CI_WB,
                            CI_BB, CI_WO, CI_BO};
    int b = blockIdx.x, k = 0;
    while (b >= bc[k]) { b -= bc[k]; k++; }
    int li = b * 256 + threadIdx.x;
    if (li >= sizes[k]) return;
    const void* p;
    switch (k) {
        case 0: p = p0; break;  case 1: p = p1; break;  case 2: p = p2; break;
        case 3: p = p3; break;  case 4: p = p4; break;  case 5: p = p5; break;
        case 6: p = p6; break;  case 7: p = p7; break;  case 8: p = p8; break;
        case 9: p = p9; break;  case 10: p = p10; break; case 11: p = p11; break;
        case 12: p = p12; break; case 13: p = p13; break; case 14: p = p14; break;
        case 15: p = p15; break; default: p = p16; break;
    }
    float v;
    if (*flagp) v = ((const float*)p)[li];
    else        v = bf2f(((const unsigned short*)p)[li]);
    ws[OFF_IN + starts[k] + li] = v;
}

// ---------------- prep_all: WicT + emb + xt + all weight packs ----------------
__global__ void prep_all(float* ws)
{
    const float* cin = ws + OFF_IN;
    int id = blockIdx.x * 256 + threadIdx.x;
    if (id < 98304) {                                 // WicT [e][768]
        int e = id / 768, g = id % 768;
        float v = (g < 384) ? cin[CI_WIA + g * 128 + e]
                            : cin[CI_WIB + (g - 384) * 128 + e];
        ws[OFF_WIC + id] = v;
    } else if (id < 622592) {                         // emb [t][b][128]
        int id2 = id - 98304;
        int e = id2 & 127;
        int tb = id2 >> 7;
        int b = tb & 63, t = tb >> 6;
        const float* xp = cin + CI_X + (b * T_ + t) * D_;
        const float* wp = cin + CI_WEMB + e * D_;
        float acc = cin[CI_BEMB + e];
        #pragma unroll
        for (int d = 0; d < 64; d += 4) {
            f32x4 xv = *(const f32x4*)(xp + d);
            f32x4 wv = *(const f32x4*)(wp + d);
            acc += xv[0]*wv[0] + xv[1]*wv[1] + xv[2]*wv[2] + xv[3]*wv[3];
        }
        ws[OFF_EMB + id2] = acc;
    } else if (id < 884736) {                         // xt [t][d][b]
        int id5 = id - 622592;
        int b = id5 & 63, d = (id5 >> 6) & 63, t = id5 >> 12;
        ws[OFF_XT + id5] = cin[CI_X + (b * 64 + t) * 64 + d];
    } else if (id < 983040) {                         // gh weights (pi-k)
        unsigned short* wpk = (unsigned short*)(ws + OFF_WPK);
        int id3 = id - 884736;
        int w = id3 / 12288, r1 = id3 % 12288;
        int nt = r1 / 2048, r2 = r1 % 2048;
        int kt = r2 / 512, r3 = r2 % 512;
        int lane = r3 >> 3, j = r3 & 7;
        int cell = w >> 2, wv = w & 3;
        int gate = nt >> 1, tt = nt & 1;
        int g = gate * 128 + wv * 32 + tt * 16 + (lane & 15);
        int k = kpi(kt * 32 + (lane >> 4) * 8 + j);
        wpk[id3] = f2bf(cin[(cell ? CI_WHB : CI_WHA) + g * 128 + k]);
    } else if (id < 999424) {                         // Wb (pi-k)
        unsigned short* bpk = (unsigned short*)(ws + OFF_BPPK);
        int id4 = id - 983040;
        int w = id4 / 2048, r = id4 % 2048;
        int kt = r / 512, lane = (r % 512) >> 3, j = r & 7;
        int e = w * 16 + (lane & 15);
        int k = kpi(kt * 32 + (lane >> 4) * 8 + j);
        bpk[id4] = f2bf(cin[CI_WB + e * 128 + k]);
    } else if (id < 1007616) {                        // Wm (true e)
        unsigned short* wmk = (unsigned short*)(ws + OFF_WMPK);
        int id6 = id - 999424;
        int nt = id6 / 2048, r = id6 % 2048;
        int kt = r / 512, lane = (r % 512) >> 3, j = r & 7;
        int d = nt * 16 + (lane & 15);
        int e = kt * 32 + (lane >> 4) * 8 + j;
        wmk[id6] = f2bf(cin[CI_WO + e] * cin[CI_WEMB + e * 64 + d]);
    } else {                                          // Wa alpha tile (pi-k)
        unsigned short* alk = (unsigned short*)(ws + OFF_WALPK);
        int id7 = id - 1007616;
        int kt = id7 / 512, lane = (id7 % 512) >> 3, j = id7 & 7;
        int k = kpi(kt * 32 + (lane >> 4) * 8 + j);
        alk[id7] = ((lane & 15) == 0) ? f2bf(cin[CI_WA + k]) : (unsigned short)0;
    }
}

// ---------------- prep_gi: LDS-staged scatter, coalesced dwordx4 dump ----------------
__global__ void prep_gi(float* ws)
{
    const float* cin = ws + OFF_IN;
    unsigned short* gipk = (unsigned short*)(ws + OFF_GIPK);
    int t = blockIdx.x >> 2;
    int chunk = blockIdx.x & 3;
    int b0 = chunk * 16;
    int tid = threadIdx.x;
    __shared__ __align__(16) float semT[128][16];
    __shared__ __align__(16) unsigned short stg[12288];   // block's gipk span
    #pragma unroll
    for (int q = 0; q < 8; q++) {
        int idx = tid + q * 256;
        int r = idx & 15, e = idx >> 4;
        semT[e][r] = ws[OFF_EMB + (size_t)((t * 64 + b0 + r) * 128) + e];
    }
    __syncthreads();
    float acc[3][16];
    #pragma unroll
    for (int g3 = 0; g3 < 3; g3++)
        #pragma unroll
        for (int r = 0; r < 16; r++) acc[g3][r] = 0.f;
    const float* wic = ws + OFF_WIC;
    #pragma unroll 2
    for (int e = 0; e < 128; e++) {
        f32x4 h0 = *(const f32x4*)&semT[e][0];
        f32x4 h1 = *(const f32x4*)&semT[e][4];
        f32x4 h2 = *(const f32x4*)&semT[e][8];
        f32x4 h3 = *(const f32x4*)&semT[e][12];
        float hv[16] = {h0[0],h0[1],h0[2],h0[3], h1[0],h1[1],h1[2],h1[3],
                        h2[0],h2[1],h2[2],h2[3], h3[0],h3[1],h3[2],h3[3]};
        float w0 = wic[e * 768 + tid];
        float w1 = wic[e * 768 + tid + 256];
        float w2 = wic[e * 768 + tid + 512];
        #pragma unroll
        for (int r = 0; r < 16; r++) {
            acc[0][r] += hv[r] * w0;
            acc[1][r] += hv[r] * w1;
            acc[2][r] += hv[r] * w2;
        }
    }
    #pragma unroll
    for (int g3 = 0; g3 < 3; g3++) {
        int g = tid + g3 * 256;
        int cellg = g / 384, gr = g % 384;
        int gate = gr / 128, kh = gr % 128;
        int wvp = kh / 32, tt2 = (kh % 32) / 16, l15p = kh % 16;
        int wq = cellg * 4 + wvp;
        float bias = cin[(cellg ? CI_BIB : CI_BIA) + gr];
        if (gate < 2) bias += cin[(cellg ? CI_BHB : CI_BHA) + gr];
        #pragma unroll
        for (int r = 0; r < 16; r++) {
            float v = acc[g3][r] + bias;
            int lane2 = (r >> 2) * 16 + l15p;
            int slot = gate * 8 + tt2 * 4 + (r & 3);
            stg[(wq * 64 + lane2) * 24 + slot] = f2bf(v);
        }
    }
    __syncthreads();
    const uint4* s4 = (const uint4*)stg;                  // 1536 uint4
    uint4* d4 = (uint4*)(gipk + (size_t)(t * 4 + chunk) * 12288);
    #pragma unroll
    for (int i = 0; i < 6; i++) d4[tid + i * 256] = s4[tid + i * 256];
}

// ---------------- fused chain kernel ----------------
// 120 WGs: (prefix p, chunk-pair). 1024 threads = 16 waves = TWO independent
// 16-row chunk chains of the SAME prefix (lockstep, shared barrier) -> 4
// waves/SIMD. VGPR budget 128: wB streamed from L2 per kt (not persistent),
// bBp/wAl in LDS, gi single-buffered, union accumulator accR[9].

__launch_bounds__(1024)
__global__ void chain_kernel(const float* ws, void* outv, const int* flagp,
                             const void* p_bha, const void* p_bhb,
                             const void* p_bb, const void* p_ba,
                             const void* p_bo, const void* p_wo)
{
    const int p = PMIN + (int)blockIdx.x / 2;
    const int pair = (int)blockIdx.x & 1;
    const int tid = threadIdx.x;
    const int lane = tid & 63;
    const int W = tid >> 6;          // 0..15
    const int half = W >> 3;
    const int w = W & 7;
    const int chunk = pair * 2 + half;
    const int cell = w >> 2;
    const int wv = w & 3;
    const int l15 = lane & 15;
    const int quad = lane >> 4;

    __shared__ __align__(16) short hbf[2][2][2][16][132];  // [half][buf][cell][row][m]
    __shared__ __align__(16) short betbf[2][2][16][132];   // [half][buf][row][e]
    __shared__ __align__(16) short sWm[4][4][64][8];
    __shared__ __align__(16) short sBp[8][4][64][8];       // Wb B-frags
    __shared__ __align__(16) short sAl[4][64][8];          // Wa alpha B-frags
    __shared__ float spaLds[2][2][16];

    const unsigned short* gipk = (const unsigned short*)(ws + OFF_GIPK);
    const unsigned short* wpk  = (const unsigned short*)(ws + OFF_WPK);
    const int flag = *flagp;

    {   // stage Wm / bBp / wAl; zero all h buffers
        const int* s2 = (const int*)(ws + OFF_WMPK);
        int* d2 = (int*)&sWm[0][0][0][0];
        for (int i = tid; i < 4096; i += 1024) d2[i] = s2[i];
        const int* s3 = (const int*)(ws + OFF_BPPK);
        int* d3 = (int*)&sBp[0][0][0][0];
        for (int i = tid; i < 8192; i += 1024) d3[i] = s3[i];
        const int* s4 = (const int*)(ws + OFF_WALPK);
        int* d4 = (int*)&sAl[0][0][0];
        for (int i = tid; i < 1024; i += 1024) d4[i] = s4[i];
        int* hz = (int*)&hbf[0][0][0][0][0];
        for (int i = tid; i < 8448; i += 1024) hz[i] = 0;
    }

    // per-lane constants
    float bhn0, bhn1, bbE, baf, bof;
    if (flag) {
        const float* bh = (const float*)(cell ? p_bhb : p_bha);
        bhn0 = bh[256 + wv * 32 + l15];
        bhn1 = bh[256 + wv * 32 + 16 + l15];
        bbE = ((const float*)p_bb)[w * 16 + l15];
        baf = ((const float*)p_ba)[0];
        bof = ((const float*)p_bo)[0];
    } else {
        const unsigned short* bh = (const unsigned short*)(cell ? p_bhb : p_bha);
        bhn0 = bf2f(bh[256 + wv * 32 + l15]);
        bhn1 = bf2f(bh[256 + wv * 32 + 16 + l15]);
        bbE = bf2f(((const unsigned short*)p_bb)[w * 16 + l15]);
        baf = bf2f(((const unsigned short*)p_ba)[0]);
        bof = bf2f(((const unsigned short*)p_bo)[0]);
    }

    float h_old[8];
    #pragma unroll
    for (int i = 0; i < 8; i++) h_old[i] = 0.f;
    // union accumulator: w<4 -> [0..3]=gAcc, [4..7]=sl4; w>=4 -> [0..7]=cAcc, [8]=slB
    float accR[9];
    #pragma unroll
    for (int i = 0; i < 9; i++) accR[i] = 0.f;

    // per-wave weight-pack base (stream source)
    const unsigned short* wpW = wpk + (size_t)w * 6 * 4 * 64 * 8 + (size_t)lane * 8;

    __syncthreads();

    for (int it = 0; it <= p + 1; it++) {
        const int j = p - it;
        const int jp = j + 1;
        const bool doGru = (j >= 0);
        const bool doAcc = (it > 0);
        const int cur = it & 1;
        const int nxt = cur ^ 1;
        const int dbuf = it & 1;

        // gi for current j (L2/L3-resident; latency covered by Phase A)
        s16x8 giv[3];
        if (doGru) {
            const unsigned short* gp =
                gipk + ((((size_t)j * 4 + chunk) * 8 + w) * 64 + lane) * 24;
            #pragma unroll
            for (int i = 0; i < 3; i++) giv[i] = *(const s16x8*)(gp + i * 8);
        }
        // prefetch x / emb for this iteration's Phase C (drained at the barrier)
        f32x4 xv, em0, em1;
        if (doAcc) {
            if (w < 4) {
                xv = *(const f32x4*)(ws + OFF_XT + ((size_t)jp * 64 + w * 16 + l15) * 64
                                     + chunk * 16 + quad * 4);
            } else {
                const int row = quad * 4 + (w - 4);
                const float* ep = ws + OFF_EMB
                                  + ((size_t)jp * 64 + chunk * 16 + row) * 128 + l15 * 8;
                em0 = *(const f32x4*)ep;
                em1 = *(const f32x4*)(ep + 4);
            }
        }

        // ---- Phase A: MFMA gates + betapre (+ alpha on w==7); wB streamed ----
        f32x4 Cg[6], Cbp, Cal;
        #pragma unroll
        for (int nt = 0; nt < 6; nt++) Cg[nt] = (f32x4){0.f,0.f,0.f,0.f};
        Cbp = (f32x4){0.f,0.f,0.f,0.f};
        Cal = (f32x4){0.f,0.f,0.f,0.f};

        #pragma unroll
        for (int kt = 0; kt < 4; kt++) {
            s16x8 wBk[6];
            #pragma unroll
            for (int nt = 0; nt < 6; nt++)
                wBk[nt] = *(const s16x8*)(wpW + (size_t)(nt * 4 + kt) * 64 * 8);
            s16x8 aA = ldA(&hbf[half][cur][0][l15][kt * 32 + quad * 8]);
            s16x8 aB = ldA(&hbf[half][cur][1][l15][kt * 32 + quad * 8]);
            s16x8 aOwn = cell ? aB : aA;
            #pragma unroll
            for (int nt = 0; nt < 6; nt++)
                Cg[nt] = __builtin_amdgcn_mfma_f32_16x16x32_bf16(aOwn, wBk[nt], Cg[nt], 0, 0, 0);
            s16x8 bbp = *(const s16x8*)&sBp[w][kt][lane][0];
            Cbp = __builtin_amdgcn_mfma_f32_16x16x32_bf16(aB, bbp, Cbp, 0, 0, 0);
            if (w == 7) {
                s16x8 wal = *(const s16x8*)&sAl[kt][lane][0];
                Cal = __builtin_amdgcn_mfma_f32_16x16x32_bf16(aA, wal, Cal, 0, 0, 0);
            }
        }

        // ---- Phase B ----
        if (w == 7 && l15 == 0) {
            #pragma unroll
            for (int reg = 0; reg < 4; reg++)
                spaLds[half][dbuf][quad * 4 + reg] = fminf(0.5f * Cal[reg] + baf, 60.f);
        }
        if (doGru) {
            #pragma unroll
            for (int reg = 0; reg < 4; reg++) {
                float hn2[2];
                #pragma unroll
                for (int tt = 0; tt < 2; tt++) {
                    float gir = bf2f((unsigned short)giv[0][tt * 4 + reg]);
                    float giz = bf2f((unsigned short)giv[1][tt * 4 + reg]);
                    float gin = bf2f((unsigned short)giv[2][tt * 4 + reg]);
                    float ghr = Cg[0 + tt][reg];
                    float ghz = Cg[2 + tt][reg];
                    float ghn = Cg[4 + tt][reg] + (tt ? bhn1 : bhn0);
                    float ho  = h_old[tt * 4 + reg];
                    float rr = sigmoidf_(gir + ghr);
                    float zz = sigmoidf_(giz + ghz);
                    float nn = tanhf_(gin + rr * ghn);
                    float hv2 = (1.f - zz) * nn + zz * ho;
                    h_old[tt * 4 + reg] = hv2;
                    hn2[tt] = hv2;
                }
                unsigned pk = (unsigned)f2bf(hn2[0]) | ((unsigned)f2bf(hn2[1]) << 16);
                *(unsigned*)&hbf[half][nxt][cell][quad * 4 + reg][wv * 32 + l15 * 2] = pk;
            }
        }
        #pragma unroll
        for (int reg = 0; reg < 4; reg++) {
            float bv = tanhf_(0.5f * Cbp[reg] + bbE);
            betbf[half][dbuf][quad * 4 + reg][w * 16 + l15] = (short)f2bf(bv);
        }

        __syncthreads();   // the ONE barrier

        // ---- Phase C: attention accumulation (scan step it-1) ----
        if (doAcc) {
            if (w < 4) {
                f32x4 ec = (f32x4){0.f,0.f,0.f,0.f};
                #pragma unroll
                for (int kt = 0; kt < 4; kt++) {
                    s16x8 a = ldA(&betbf[half][dbuf][l15][kt * 32 + quad * 8]);
                    s16x8 bw = *(const s16x8*)&sWm[w][kt][lane][0];
                    ec = __builtin_amdgcn_mfma_f32_16x16x32_bf16(a, bw, ec, 0, 0, 0);
                }
                #pragma unroll
                for (int reg = 0; reg < 4; reg++) {
                    float we = __expf(spaLds[half][dbuf][quad * 4 + reg]);
                    accR[4 + reg] += we;
                    accR[reg] += we * ec[reg] * xv[reg];
                }
            } else {
                const int row = quad * 4 + (w - 4);
                float we = __expf(spaLds[half][dbuf][row]);
                accR[8] += we;
                const short* bp2 = &betbf[half][dbuf][row][l15 * 8];
                s16x4 blo = *(const s16x4*)bp2;
                s16x4 bhi = *(const s16x4*)(bp2 + 4);
                #pragma unroll
                for (int v = 0; v < 4; v++)
                    accR[v] += we * bf2f((unsigned short)blo[v]) * em0[v];
                #pragma unroll
                for (int v = 0; v < 4; v++)
                    accR[4 + v] += we * bf2f((unsigned short)bhi[v]) * em1[v];
            }
        }
    }

    // ---- epilogue ----
    if (w >= 4) {       // pred = (c . Wo)/sl + bo
        const int row = quad * 4 + (w - 4);
        float wo8[8];
        if (flag) {
            const float* wp = (const float*)p_wo + l15 * 8;
            #pragma unroll
            for (int v = 0; v < 8; v++) wo8[v] = wp[v];
        } else {
            const unsigned short* wp = (const unsigned short*)p_wo + l15 * 8;
            #pragma unroll
            for (int v = 0; v < 8; v++) wo8[v] = bf2f(wp[v]);
        }
        float part = 0.f;
        #pragma unroll
        for (int v = 0; v < 8; v++) part += accR[v] * wo8[v];
        part += __shfl_xor(part, 1);
        part += __shfl_xor(part, 2);
        part += __shfl_xor(part, 4);
        part += __shfl_xor(part, 8);
        if (l15 == 0) {
            int bglob = chunk * 16 + row;
            float pr = part / accR[8] + bof;
            size_t oi = (size_t)bglob * NPOUT + (p - PMIN);
            if (flag) ((float*)outv)[oi] = pr;
            else      ((bf16*)outv)[oi] = __float2bfloat16(pr);
        }
    } else {            // weight = g/sl/(p+1)
        const float invt = 1.f / (float)(p + 1);
        #pragma unroll
        for (int reg = 0; reg < 4; reg++) {
            int row = quad * 4 + reg;
            int bglob = chunk * 16 + row;
            float gv = accR[reg] / accR[4 + reg] * invt;
            size_t oi = (size_t)B_ * NPOUT
                      + ((size_t)bglob * NPOUT + (p - PMIN)) * 64 + w * 16 + l15;
            if (flag) ((float*)outv)[oi] = gv;
            else      ((bf16*)outv)[oi] = __float2bfloat16(gv);
        }
    }
}

// ---------------- launch ----------------
extern "C" void kernel_launch(void* const* d_in, const int* in_sizes, int n_in,
                              void* d_out, int out_size, void* d_ws, size_t ws_size,
                              hipStream_t stream)
{
    float* ws = (float*)d_ws;
    int* flagp = (int*)(ws + OFF_FLAG);

    hipLaunchKernelGGL(detect_dtype, dim3(1), dim3(256), 0, stream,
                       (const unsigned short*)d_in[0], flagp);
    hipLaunchKernelGGL(convert_inputs, dim3(1902), dim3(256), 0, stream,
                       d_in[0], d_in[1], d_in[2], d_in[3], d_in[4], d_in[5],
                       d_in[6], d_in[7], d_in[8], d_in[9], d_in[10], d_in[11],
                       d_in[12], d_in[13], d_in[14], d_in[15], d_in[16],
                       ws, flagp);
    hipLaunchKernelGGL(prep_all, dim3(3944), dim3(256), 0, stream, ws);
    hipLaunchKernelGGL(prep_gi,  dim3(256),  dim3(256), 0, stream, ws);
    hipLaunchKernelGGL(chain_kernel, dim3(NPOUT * 2), dim3(1024), 0, stream,
                       ws, d_out, flagp,
                       d_in[6], d_in[10], d_in[14], d_in[12], d_in[16], d_in[15]);
}

// Round 10
// 354.500 us; speedup vs baseline: 3.5965x; 2.1172x over previous
//
#include <hip/hip_runtime.h>
#include <hip/hip_bf16.h>
#include <math.h>

// Problem constants (reference: B,T,D=64, E=HA=HB=128, OUT=1, short=2)
#define B_ 64
#define T_ 64
#define D_ 64
#define PMIN 3        // short+1
#define NPOUT 60      // T-2-short
#define NCHUNK 8      // batch chunks of 8 per prefix

typedef __hip_bfloat16 bf16;
typedef __attribute__((ext_vector_type(4))) short s16x4;
typedef __attribute__((ext_vector_type(8))) short s16x8;
typedef __attribute__((ext_vector_type(4))) float f32x4;

// ---- workspace layout (fp32 element offsets; packs 16B-aligned) ----
#define OFF_EMB   0                      // [t][b][128] fp32
#define OFF_WIC   524288                 // WicT [e][768] fp32
#define OFF_XT    622592                 // xt [t][d][b] fp32
#define OFF_GIPK  884736                 // bf16 [t][chunk8][w][lane32][24]
#define OFF_WPK   2457600                // bf16 [w][nt6][kt][lane][8] (pi-k)
#define OFF_BPPK  2506752                // bf16 [w8][kt][lane][8]     (pi-k)
#define OFF_WMPK  2514944                // bf16 [nt4][kt][lane][8]    (true e)
#define OFF_WALPK 2519040                // bf16 [kt][lane][8]         (pi-k)
#define OFF_FLAG  2520064

__device__ __forceinline__ float bf2f(unsigned short u) {
    union { float f; unsigned u32; } x; x.u32 = ((unsigned)u) << 16; return x.f;
}
__device__ __forceinline__ unsigned short f2bf(float f) {
    union { float f; unsigned u; } x; x.f = f;
    unsigned r = x.u + 0x7FFFu + ((x.u >> 16) & 1u);
    return (unsigned short)(r >> 16);
}
__device__ __forceinline__ float LDF(const void* p, int i, int flag) {
    return flag ? ((const float*)p)[i] : bf2f(((const unsigned short*)p)[i]);
}
__device__ __forceinline__ float sigmoidf_(float v) { return 1.f / (1.f + __expf(-v)); }
__device__ __forceinline__ float tanhf_(float v) {
    float e = __expf(-2.f * fabsf(v));
    float t = (1.f - e) / (1.f + e);
    return copysignf(t, v);
}
// k-dimension permutation: stored slot s -> true index (pairs (l,t) adjacent)
__device__ __forceinline__ int kpi(int s) {
    return (s & ~31) | ((s & 1) << 4) | ((s & 31) >> 1);
}
__device__ __forceinline__ s16x8 ldA(const short* p) {   // 8B-aligned 16B LDS read
    s16x4 lo = *(const s16x4*)p;
    s16x4 hi = *(const s16x4*)(p + 4);
    return __builtin_shufflevector(lo, hi, 0, 1, 2, 3, 4, 5, 6, 7);
}

// ---------------- dtype detection ----------------
__global__ void detect_dtype(const unsigned short* xr, int* flag)
{
    int tid = threadIdx.x;
    int bad = 0;
    for (int i = tid; i < 4096; i += 256) {
        int ex = (xr[i] >> 7) & 0xFF;
        if (ex >= 140) bad++;
    }
    __shared__ int s[256];
    s[tid] = bad;
    __syncthreads();
    for (int st = 128; st > 0; st >>= 1) {
        if (tid < st) s[tid] += s[tid + st];
        __syncthreads();
    }
    if (tid == 0) *flag = (s[0] > 4) ? 1 : 0;
}

// ---------------- prep_all: reads RAW inputs (flag-branched) ----------------
// sections: wic [0,98304) | emb [98304,622592) | xt [622592,884736)
//           wpk [884736,983040) | bppk [983040,999424) | wmpk [999424,1007616)
//           walpk [1007616,1009664)  -> 3944 blocks x 256
__global__ void prep_all(const void* p_x, const void* p_wemb, const void* p_bemb,
                         const void* p_wia, const void* p_wha,
                         const void* p_wib, const void* p_whb,
                         const void* p_wa, const void* p_wb, const void* p_wo,
                         float* ws, const int* flagp)
{
    const int flag = *flagp;
    int id = blockIdx.x * 256 + threadIdx.x;
    if (id < 98304) {                                 // WicT [e][768]
        int e = id / 768, g = id % 768;
        float v = (g < 384) ? LDF(p_wia, g * 128 + e, flag)
                            : LDF(p_wib, (g - 384) * 128 + e, flag);
        ws[OFF_WIC + id] = v;
    } else if (id < 622592) {                         // emb [t][b][128]
        int id2 = id - 98304;
        int e = id2 & 127;
        int tb = id2 >> 7;
        int b = tb & 63, t = tb >> 6;
        float acc = LDF(p_bemb, e, flag);
        if (flag) {
            const float* xp = (const float*)p_x + (b * T_ + t) * D_;
            const float* wp = (const float*)p_wemb + e * D_;
            #pragma unroll
            for (int d = 0; d < 64; d += 4) {
                f32x4 xv = *(const f32x4*)(xp + d);
                f32x4 wv = *(const f32x4*)(wp + d);
                acc += xv[0]*wv[0] + xv[1]*wv[1] + xv[2]*wv[2] + xv[3]*wv[3];
            }
        } else {
            const unsigned short* xp = (const unsigned short*)p_x + (b * T_ + t) * D_;
            const unsigned short* wp = (const unsigned short*)p_wemb + e * D_;
            for (int d = 0; d < 64; d++) acc += bf2f(xp[d]) * bf2f(wp[d]);
        }
        ws[OFF_EMB + id2] = acc;
    } else if (id < 884736) {                         // xt [t][d][b]
        int id5 = id - 622592;
        int b = id5 & 63, d = (id5 >> 6) & 63, t = id5 >> 12;
        ws[OFF_XT + id5] = LDF(p_x, (b * 64 + t) * 64 + d, flag);
    } else if (id < 983040) {                         // gh weights (pi-k)
        unsigned short* wpk = (unsigned short*)(ws + OFF_WPK);
        int id3 = id - 884736;
        int w = id3 / 12288, r1 = id3 % 12288;
        int nt = r1 / 2048, r2 = r1 % 2048;
        int kt = r2 / 512, r3 = r2 % 512;
        int lane = r3 >> 3, j = r3 & 7;
        int cell = w >> 2, wv = w & 3;
        int gate = nt >> 1, tt = nt & 1;
        int g = gate * 128 + wv * 32 + tt * 16 + (lane & 15);
        int k = kpi(kt * 32 + (lane >> 4) * 8 + j);
        wpk[id3] = f2bf(LDF(cell ? p_whb : p_wha, g * 128 + k, flag));
    } else if (id < 999424) {                         // Wb (pi-k)
        unsigned short* bpk = (unsigned short*)(ws + OFF_BPPK);
        int id4 = id - 983040;
        int w = id4 / 2048, r = id4 % 2048;
        int kt = r / 512, lane = (r % 512) >> 3, j = r & 7;
        int e = w * 16 + (lane & 15);
        int k = kpi(kt * 32 + (lane >> 4) * 8 + j);
        bpk[id4] = f2bf(LDF(p_wb, e * 128 + k, flag));
    } else if (id < 1007616) {                        // Wm (true e)
        unsigned short* wmk = (unsigned short*)(ws + OFF_WMPK);
        int id6 = id - 999424;
        int nt = id6 / 2048, r = id6 % 2048;
        int kt = r / 512, lane = (r % 512) >> 3, j = r & 7;
        int d = nt * 16 + (lane & 15);
        int e = kt * 32 + (lane >> 4) * 8 + j;
        wmk[id6] = f2bf(LDF(p_wo, e, flag) * LDF(p_wemb, e * 64 + d, flag));
    } else {                                          // Wa alpha tile (pi-k)
        unsigned short* alk = (unsigned short*)(ws + OFF_WALPK);
        int id7 = id - 1007616;
        int kt = id7 / 512, lane = (id7 % 512) >> 3, j = id7 & 7;
        int k = kpi(kt * 32 + (lane >> 4) * 8 + j);
        alk[id7] = ((lane & 15) == 0) ? f2bf(LDF(p_wa, k, flag)) : (unsigned short)0;
    }
}

// ---------------- prep_gi: 8-row chunks; LDS-staged, coalesced dump ----------------
__global__ void prep_gi(float* ws, const void* p_bia, const void* p_bha,
                        const void* p_bib, const void* p_bhb, const int* flagp)
{
    const int flag = *flagp;
    unsigned short* gipk = (unsigned short*)(ws + OFF_GIPK);
    int t = blockIdx.x >> 3;
    int chunk = blockIdx.x & 7;
    int b0 = chunk * 8;
    int tid = threadIdx.x;
    __shared__ __align__(16) float semT[128][8];
    __shared__ __align__(16) unsigned short stg[6144];   // [wq8][lane32][24]
    #pragma unroll
    for (int q = 0; q < 4; q++) {
        int idx = tid + q * 256;                          // 1024 = 128e x 8r
        int r = idx & 7, e = idx >> 3;
        semT[e][r] = ws[OFF_EMB + (size_t)((t * 64 + b0 + r) * 128) + e];
    }
    __syncthreads();
    float acc[3][8];
    #pragma unroll
    for (int g3 = 0; g3 < 3; g3++)
        #pragma unroll
        for (int r = 0; r < 8; r++) acc[g3][r] = 0.f;
    const float* wic = ws + OFF_WIC;
    #pragma unroll 2
    for (int e = 0; e < 128; e++) {
        f32x4 h0 = *(const f32x4*)&semT[e][0];
        f32x4 h1 = *(const f32x4*)&semT[e][4];
        float hv[8] = {h0[0],h0[1],h0[2],h0[3], h1[0],h1[1],h1[2],h1[3]};
        float w0 = wic[e * 768 + tid];
        float w1 = wic[e * 768 + tid + 256];
        float w2 = wic[e * 768 + tid + 512];
        #pragma unroll
        for (int r = 0; r < 8; r++) {
            acc[0][r] += hv[r] * w0;
            acc[1][r] += hv[r] * w1;
            acc[2][r] += hv[r] * w2;
        }
    }
    #pragma unroll
    for (int g3 = 0; g3 < 3; g3++) {
        int g = tid + g3 * 256;
        int cellg = g / 384, gr = g % 384;
        int gate = gr / 128, kh = gr % 128;
        int wvp = kh / 32, tt2 = (kh % 32) / 16, l15p = kh % 16;
        int wq = cellg * 4 + wvp;
        float bias = LDF(cellg ? p_bib : p_bia, gr, flag);
        if (gate < 2) bias += LDF(cellg ? p_bhb : p_bha, gr, flag);
        #pragma unroll
        for (int r = 0; r < 8; r++) {
            float v = acc[g3][r] + bias;
            int lane2 = (r >> 2) * 16 + l15p;             // 0..31
            int slot = gate * 8 + tt2 * 4 + (r & 3);
            stg[(wq * 32 + lane2) * 24 + slot] = f2bf(v);
        }
    }
    __syncthreads();
    // stg = 6144 shorts = 12288 B = 768 uint4  (R9 BUG: copied only 384 -> half
    // of every block span, all cell-b gi, was left as workspace poison)
    const uint4* s4 = (const uint4*)stg;
    uint4* d4 = (uint4*)(gipk + (size_t)(t * 8 + chunk) * 6144);
    for (int i = tid; i < 768; i += 256) d4[i] = s4[i];
}

// ---------------- fused chain kernel ----------------
// 480 WGs: (prefix p, batch chunk of 8). 512 threads = 8 waves, M=8 (rows
// 8-15 of h/beta pinned to zero). LDS 42 KB + VGPR 128 -> 2 WGs/CU = 4
// waves/SIMD of de-correlated work. Long prefixes dispatched first.
// wave w = cell*4+wv: 6 gate n-tiles + betapre tile; w==7 also alpha tile.

__launch_bounds__(512, 2)
__global__ void chain_kernel(const float* ws, void* outv, const int* flagp,
                             const void* p_bha, const void* p_bhb,
                             const void* p_bb, const void* p_ba,
                             const void* p_bo, const void* p_wo)
{
    const int p = PMIN + (NPOUT - 1) - (int)blockIdx.x / NCHUNK;
    const int chunk = (int)blockIdx.x % NCHUNK;
    const int tid = threadIdx.x;
    const int lane = tid & 63;
    const int w = tid >> 6;
    const int cell = w >> 2;
    const int wv = w & 3;
    const int l15 = lane & 15;
    const int quad = lane >> 4;

    __shared__ __align__(16) short hbf[2][2][16][132];   // [buf][cell][row][m] pi-k
    __shared__ __align__(16) short betbf[2][16][132];    // true-e order
    __shared__ __align__(16) short sWm[4][4][64][8];
    __shared__ float spaLds[2][8];

    const unsigned short* gipk = (const unsigned short*)(ws + OFF_GIPK);
    const unsigned short* wpk  = (const unsigned short*)(ws + OFF_WPK);
    const unsigned short* bpk  = (const unsigned short*)(ws + OFF_BPPK);
    const unsigned short* alk  = (const unsigned short*)(ws + OFF_WALPK);
    const int flag = *flagp;

    {   // stage Wm; zero ALL h and beta buffers (rows 8-15 stay zero forever)
        const int* s2 = (const int*)(ws + OFF_WMPK);
        int* d2 = (int*)&sWm[0][0][0][0];
        for (int i = tid; i < 4096; i += 512) d2[i] = s2[i];
        int* hz = (int*)&hbf[0][0][0][0];
        for (int i = tid; i < 4224; i += 512) hz[i] = 0;
        int* bz = (int*)&betbf[0][0][0];
        for (int i = tid; i < 2112; i += 512) bz[i] = 0;
    }

    // persistent B-fragment registers
    s16x8 wB[6][4];
    #pragma unroll
    for (int nt = 0; nt < 6; nt++)
        #pragma unroll
        for (int kt = 0; kt < 4; kt++)
            wB[nt][kt] = *(const s16x8*)(wpk + (((w * 6 + nt) * 4 + kt) * 64 + lane) * 8);
    s16x8 bBp[4], wAl[4];
    #pragma unroll
    for (int kt = 0; kt < 4; kt++) {
        bBp[kt] = *(const s16x8*)(bpk + ((w * 4 + kt) * 64 + lane) * 8);
        wAl[kt] = *(const s16x8*)(alk + (kt * 64 + lane) * 8);
    }

    // per-lane constants
    float bhn0, bhn1, bbE, baf, bof;
    if (flag) {
        const float* bh = (const float*)(cell ? p_bhb : p_bha);
        bhn0 = bh[256 + wv * 32 + l15];
        bhn1 = bh[256 + wv * 32 + 16 + l15];
        bbE = ((const float*)p_bb)[w * 16 + l15];
        baf = ((const float*)p_ba)[0];
        bof = ((const float*)p_bo)[0];
    } else {
        const unsigned short* bh = (const unsigned short*)(cell ? p_bhb : p_bha);
        bhn0 = bf2f(bh[256 + wv * 32 + l15]);
        bhn1 = bf2f(bh[256 + wv * 32 + 16 + l15]);
        bbE = bf2f(((const unsigned short*)p_bb)[w * 16 + l15]);
        baf = bf2f(((const unsigned short*)p_ba)[0]);
        bof = bf2f(((const unsigned short*)p_bo)[0]);
    }

    float h_old[8];
    #pragma unroll
    for (int i = 0; i < 8; i++) h_old[i] = 0.f;
    // union accumulator: w<4 -> [0..3]=gAcc, [4..7]=sl4; w>=4 -> [0..7]=cAcc, [8]=slB
    float accR[9];
    #pragma unroll
    for (int i = 0; i < 9; i++) accR[i] = 0.f;

    __syncthreads();

    for (int it = 0; it <= p + 1; it++) {
        const int j = p - it;
        const int jp = j + 1;
        const bool doGru = (j >= 0);
        const bool doAcc = (it > 0);
        const int cur = it & 1;
        const int nxt = cur ^ 1;
        const int dbuf = it & 1;

        // gi for current j (L2-resident; latency covered by Phase A)
        s16x8 giv[3];
        if (doGru) {
            const unsigned short* gp =
                gipk + ((((size_t)j * 8 + chunk) * 8 + w) * 32 + (lane & 31)) * 24;
            #pragma unroll
            for (int i = 0; i < 3; i++) giv[i] = *(const s16x8*)(gp + i * 8);
        }
        // prefetch x / emb for this iteration's Phase C
        f32x4 xv, em0, em1;
        if (doAcc) {
            if (w < 4) {
                xv = *(const f32x4*)(ws + OFF_XT + ((size_t)jp * 64 + w * 16 + l15) * 64
                                     + chunk * 8 + (quad & 1) * 4);
            } else {
                const int row8 = (quad * 4 + (w - 4)) & 7;
                const float* ep = ws + OFF_EMB
                                  + ((size_t)jp * 64 + chunk * 8 + row8) * 128 + l15 * 8;
                em0 = *(const f32x4*)ep;
                em1 = *(const f32x4*)(ep + 4);
            }
        }

        // ---- Phase A: MFMA gates + betapre (+ alpha on w==7) ----
        f32x4 Cg[6], Cbp, Cal;
        #pragma unroll
        for (int nt = 0; nt < 6; nt++) Cg[nt] = (f32x4){0.f,0.f,0.f,0.f};
        Cbp = (f32x4){0.f,0.f,0.f,0.f};
        Cal = (f32x4){0.f,0.f,0.f,0.f};

        #pragma unroll
        for (int kt = 0; kt < 4; kt++) {
            s16x8 aB = ldA(&hbf[cur][1][l15][kt * 32 + quad * 8]);
            s16x8 aA;
            if (cell == 0 || w == 7) aA = ldA(&hbf[cur][0][l15][kt * 32 + quad * 8]);
            else aA = aB;
            s16x8 aOwn = cell ? aB : aA;
            #pragma unroll
            for (int nt = 0; nt < 6; nt++)
                Cg[nt] = __builtin_amdgcn_mfma_f32_16x16x32_bf16(aOwn, wB[nt][kt], Cg[nt], 0, 0, 0);
            Cbp = __builtin_amdgcn_mfma_f32_16x16x32_bf16(aB, bBp[kt], Cbp, 0, 0, 0);
            if (w == 7)
                Cal = __builtin_amdgcn_mfma_f32_16x16x32_bf16(aA, wAl[kt], Cal, 0, 0, 0);
        }

        // ---- Phase B ----
        if (w == 7 && l15 == 0 && quad < 2) {
            #pragma unroll
            for (int reg = 0; reg < 4; reg++)
                spaLds[dbuf][quad * 4 + reg] = fminf(0.5f * Cal[reg] + baf, 60.f);
        }
        if (doGru && quad < 2) {
            #pragma unroll
            for (int reg = 0; reg < 4; reg++) {
                float hn2[2];
                #pragma unroll
                for (int tt = 0; tt < 2; tt++) {
                    float gir = bf2f((unsigned short)giv[0][tt * 4 + reg]);
                    float giz = bf2f((unsigned short)giv[1][tt * 4 + reg]);
                    float gin = bf2f((unsigned short)giv[2][tt * 4 + reg]);
                    float ghr = Cg[0 + tt][reg];
                    float ghz = Cg[2 + tt][reg];
                    float ghn = Cg[4 + tt][reg] + (tt ? bhn1 : bhn0);
                    float ho  = h_old[tt * 4 + reg];
                    float rr = sigmoidf_(gir + ghr);
                    float zz = sigmoidf_(giz + ghz);
                    float nn = tanhf_(gin + rr * ghn);
                    float hv2 = (1.f - zz) * nn + zz * ho;
                    h_old[tt * 4 + reg] = hv2;
                    hn2[tt] = hv2;
                }
                unsigned pk = (unsigned)f2bf(hn2[0]) | ((unsigned)f2bf(hn2[1]) << 16);
                *(unsigned*)&hbf[nxt][cell][quad * 4 + reg][wv * 32 + l15 * 2] = pk;
            }
        }
        if (quad < 2) {
            #pragma unroll
            for (int reg = 0; reg < 4; reg++) {
                float bv = tanhf_(0.5f * Cbp[reg] + bbE);
                betbf[dbuf][quad * 4 + reg][w * 16 + l15] = (short)f2bf(bv);
            }
        }

        __syncthreads();   // the ONE barrier

        // ---- Phase C: attention accumulation (scan step it-1) ----
        if (doAcc) {
            if (w < 4) {
                f32x4 ec = (f32x4){0.f,0.f,0.f,0.f};
                #pragma unroll
                for (int kt = 0; kt < 4; kt++) {
                    s16x8 a = ldA(&betbf[dbuf][l15][kt * 32 + quad * 8]);
                    s16x8 bw = *(const s16x8*)&sWm[w][kt][lane][0];
                    ec = __builtin_amdgcn_mfma_f32_16x16x32_bf16(a, bw, ec, 0, 0, 0);
                }
                #pragma unroll
                for (int reg = 0; reg < 4; reg++) {
                    float we = __expf(spaLds[dbuf][(quad * 4 + reg) & 7]);
                    accR[4 + reg] += we;
                    accR[reg] += we * ec[reg] * xv[reg];
                }
            } else {
                const int row8 = (quad * 4 + (w - 4)) & 7;
                float we = __expf(spaLds[dbuf][row8]);
                accR[8] += we;
                const short* bp2 = &betbf[dbuf][row8][l15 * 8];
                s16x4 blo = *(const s16x4*)bp2;
                s16x4 bhi = *(const s16x4*)(bp2 + 4);
                #pragma unroll
                for (int v = 0; v < 4; v++)
                    accR[v] += we * bf2f((unsigned short)blo[v]) * em0[v];
                #pragma unroll
                for (int v = 0; v < 4; v++)
                    accR[4 + v] += we * bf2f((unsigned short)bhi[v]) * em1[v];
            }
        }
    }

    // ---- epilogue ----
    if (w >= 4) {       // pred = (c . Wo)/sl + bo
        const int row = quad * 4 + (w - 4);
        float wo8[8];
        if (flag) {
            const float* wp = (const float*)p_wo + l15 * 8;
            #pragma unroll
            for (int v = 0; v < 8; v++) wo8[v] = wp[v];
        } else {
            const unsigned short* wp = (const unsigned short*)p_wo + l15 * 8;
            #pragma unroll
            for (int v = 0; v < 8; v++) wo8[v] = bf2f(wp[v]);
        }
        float part = 0.f;
        #pragma unroll
        for (int v = 0; v < 8; v++) part += accR[v] * wo8[v];
        part += __shfl_xor(part, 1);
        part += __shfl_xor(part, 2);
        part += __shfl_xor(part, 4);
        part += __shfl_xor(part, 8);
        if (l15 == 0 && row < 8) {
            int bglob = chunk * 8 + row;
            float pr = part / accR[8] + bof;
            size_t oi = (size_t)bglob * NPOUT + (p - PMIN);
            if (flag) ((float*)outv)[oi] = pr;
            else      ((bf16*)outv)[oi] = __float2bfloat16(pr);
        }
    } else if (quad < 2) {   // weight = g/sl/(p+1), rows 0..7
        const float invt = 1.f / (float)(p + 1);
        #pragma unroll
        for (int reg = 0; reg < 4; reg++) {
            int row = quad * 4 + reg;
            int bglob = chunk * 8 + row;
            float gv = accR[reg] / accR[4 + reg] * invt;
            size_t oi = (size_t)B_ * NPOUT
                      + ((size_t)bglob * NPOUT + (p - PMIN)) * 64 + w * 16 + l15;
            if (flag) ((float*)outv)[oi] = gv;
            else      ((bf16*)outv)[oi] = __float2bfloat16(gv);
        }
    }
}

// ---------------- launch ----------------
extern "C" void kernel_launch(void* const* d_in, const int* in_sizes, int n_in,
                              void* d_out, int out_size, void* d_ws, size_t ws_size,
                              hipStream_t stream)
{
    float* ws = (float*)d_ws;
    int* flagp = (int*)(ws + OFF_FLAG);

    hipLaunchKernelGGL(detect_dtype, dim3(1), dim3(256), 0, stream,
                       (const unsigned short*)d_in[0], flagp);
    hipLaunchKernelGGL(prep_all, dim3(3944), dim3(256), 0, stream,
                       d_in[0], d_in[1], d_in[2], d_in[3], d_in[4],
                       d_in[7], d_in[8], d_in[11], d_in[13], d_in[15],
                       ws, flagp);
    hipLaunchKernelGGL(prep_gi, dim3(512), dim3(256), 0, stream,
                       ws, d_in[5], d_in[6], d_in[9], d_in[10], flagp);
    hipLaunchKernelGGL(chain_kernel, dim3(NPOUT * NCHUNK), dim3(512), 0, stream,
                       ws, d_out, flagp,
                       d_in[6], d_in[10], d_in[14], d_in[12], d_in[16], d_in[15]);
}

// Round 11
// 308.382 us; speedup vs baseline: 4.1344x; 1.1495x over previous
//
#include <hip/hip_runtime.h>
#include <hip/hip_bf16.h>
#include <math.h>

// Problem constants (reference: B,T,D=64, E=HA=HB=128, OUT=1, short=2)
#define B_ 64
#define T_ 64
#define D_ 64
#define PMIN 3        // short+1
#define NPOUT 60      // T-2-short
#define NCHUNK 8      // batch chunks of 8 per prefix

#define LOG2E     1.4426950408889634f
#define TWOLOG2E  2.8853900817779268f

typedef __hip_bfloat16 bf16;
typedef __attribute__((ext_vector_type(4))) short s16x4;
typedef __attribute__((ext_vector_type(8))) short s16x8;
typedef __attribute__((ext_vector_type(4))) float f32x4;

// ---- workspace layout (fp32 element offsets; packs 16B-aligned) ----
#define OFF_EMB   0                      // [t][b][128] fp32 (written by prep_gi)
#define OFF_WIC2  524288                 // wic2 [g768][e128] fp32 (raw Wi_a||Wi_b)
#define OFF_XT    622592                 // xt [t][d][b] fp32
#define OFF_GIPK  884736                 // bf16 [t][chunk8][w][lane32][24] (prescaled)
#define OFF_WPK   2457600                // bf16 [w][nt6][kt][lane][8] (pi-k, prescaled)
#define OFF_BPPK  2506752                // bf16 [w8][kt][lane][8]     (pi-k, x log2e)
#define OFF_WMPK  2514944                // bf16 [nt4][kt][lane][8]    (true e)
#define OFF_WALPK 2519040                // bf16 [kt][lane][8]         (pi-k, x 0.5log2e)
#define OFF_FLAG  2520064

__device__ __forceinline__ float bf2f(unsigned short u) {
    union { float f; unsigned u32; } x; x.u32 = ((unsigned)u) << 16; return x.f;
}
__device__ __forceinline__ unsigned short f2bf(float f) {
    union { float f; unsigned u; } x; x.f = f;
    unsigned r = x.u + 0x7FFFu + ((x.u >> 16) & 1u);
    return (unsigned short)(r >> 16);
}
__device__ __forceinline__ float LDF(const void* p, int i, int flag) {
    return flag ? ((const float*)p)[i] : bf2f(((const unsigned short*)p)[i]);
}
// cheap activations on prescaled args (see prep: args arrive in log2 domain)
__device__ __forceinline__ float sig2(float xneg) {        // sigmoid, arg = -log2e*x
    return __builtin_amdgcn_rcpf(1.f + __builtin_exp2f(xneg));
}
__device__ __forceinline__ float tanh2(float x2) {         // tanh, arg = 2log2e*x
    return 1.f - 2.f * __builtin_amdgcn_rcpf(1.f + __builtin_exp2f(x2));
}
// k-dimension permutation: stored slot s -> true index (pairs (l,t) adjacent)
__device__ __forceinline__ int kpi(int s) {
    return (s & ~31) | ((s & 1) << 4) | ((s & 31) >> 1);
}

// ---------------- dtype detection ----------------
__global__ void detect_dtype(const unsigned short* xr, int* flag)
{
    int tid = threadIdx.x;
    int bad = 0;
    for (int i = tid; i < 4096; i += 256) {
        int ex = (xr[i] >> 7) & 0xFF;
        if (ex >= 140) bad++;
    }
    __shared__ int s[256];
    s[tid] = bad;
    __syncthreads();
    for (int st = 128; st > 0; st >>= 1) {
        if (tid < st) s[tid] += s[tid + st];
        __syncthreads();
    }
    if (tid == 0) *flag = (s[0] > 4) ? 1 : 0;
}

// ---------------- prep_all: copies/packs only (no emb) ----------------
// sections: wic2 [0,98304) | xt [98304,360448) | wpk [360448,458752)
//           bppk [458752,475136) | wmpk [475136,483328) | walpk [483328,485376)
// 1896 blocks x 256
__global__ void prep_all(const void* p_x, const void* p_wemb,
                         const void* p_wia, const void* p_wib,
                         const void* p_wha, const void* p_whb,
                         const void* p_wa, const void* p_wb, const void* p_wo,
                         float* ws, const int* flagp)
{
    const int flag = *flagp;
    int id = blockIdx.x * 256 + threadIdx.x;
    if (id < 98304) {                                 // wic2 [g][e] straight convert
        float v = (id < 49152) ? LDF(p_wia, id, flag)
                               : LDF(p_wib, id - 49152, flag);
        ws[OFF_WIC2 + id] = v;
    } else if (id < 360448) {                         // xt [t][d][b]
        int id5 = id - 98304;
        int b = id5 & 63, d = (id5 >> 6) & 63, t = id5 >> 12;
        ws[OFF_XT + id5] = LDF(p_x, (b * 64 + t) * 64 + d, flag);
    } else if (id < 458752) {                         // gh weights (pi-k, prescaled)
        unsigned short* wpk = (unsigned short*)(ws + OFF_WPK);
        int id3 = id - 360448;
        int w = id3 / 12288, r1 = id3 % 12288;
        int nt = r1 / 2048, r2 = r1 % 2048;
        int kt = r2 / 512, r3 = r2 % 512;
        int lane = r3 >> 3, j = r3 & 7;
        int cell = w >> 2, wv = w & 3;
        int gate = nt >> 1, tt = nt & 1;
        int g = gate * 128 + wv * 32 + tt * 16 + (lane & 15);
        int k = kpi(kt * 32 + (lane >> 4) * 8 + j);
        float sc = (gate < 2) ? -LOG2E : TWOLOG2E;
        wpk[id3] = f2bf(sc * LDF(cell ? p_whb : p_wha, g * 128 + k, flag));
    } else if (id < 475136) {                         // Wb (pi-k, x log2e)
        unsigned short* bpk = (unsigned short*)(ws + OFF_BPPK);
        int id4 = id - 458752;
        int w = id4 / 2048, r = id4 % 2048;
        int kt = r / 512, lane = (r % 512) >> 3, j = r & 7;
        int e = w * 16 + (lane & 15);
        int k = kpi(kt * 32 + (lane >> 4) * 8 + j);
        bpk[id4] = f2bf(LOG2E * LDF(p_wb, e * 128 + k, flag));
    } else if (id < 483328) {                         // Wm (true e, unscaled)
        unsigned short* wmk = (unsigned short*)(ws + OFF_WMPK);
        int id6 = id - 475136;
        int nt = id6 / 2048, r = id6 % 2048;
        int kt = r / 512, lane = (r % 512) >> 3, j = r & 7;
        int d = nt * 16 + (lane & 15);
        int e = kt * 32 + (lane >> 4) * 8 + j;
        wmk[id6] = f2bf(LDF(p_wo, e, flag) * LDF(p_wemb, e * 64 + d, flag));
    } else {                                          // Wa alpha tile (pi-k, x 0.5log2e)
        unsigned short* alk = (unsigned short*)(ws + OFF_WALPK);
        int id7 = id - 483328;
        int kt = id7 / 512, lane = (id7 % 512) >> 3, j = id7 & 7;
        int k = kpi(kt * 32 + (lane >> 4) * 8 + j);
        alk[id7] = ((lane & 15) == 0) ? f2bf(0.5f * LOG2E * LDF(p_wa, k, flag))
                                      : (unsigned short)0;
    }
}

// ---------------- prep_gi: computes emb in-kernel, then gi (prescaled) ----------------
// 512 blocks = (t, chunk8) x 256 threads.
__global__ void prep_gi(float* ws, const void* p_x, const void* p_wemb,
                        const void* p_bemb, const void* p_bia, const void* p_bha,
                        const void* p_bib, const void* p_bhb, const int* flagp)
{
    const int flag = *flagp;
    unsigned short* gipk = (unsigned short*)(ws + OFF_GIPK);
    int t = blockIdx.x >> 3;
    int chunk = blockIdx.x & 7;
    int b0 = chunk * 8;
    int tid = threadIdx.x;
    __shared__ __align__(16) float sX[8][64];
    __shared__ __align__(16) float sWe[128][64];
    __shared__ __align__(16) float semT2[8][132];
    __shared__ __align__(16) unsigned short stg[6144];

    for (int i = tid; i < 512; i += 256) {
        int r = i >> 6, d = i & 63;
        sX[r][d] = LDF(p_x, ((b0 + r) * 64 + t) * 64 + d, flag);
    }
    for (int i = tid; i < 8192; i += 256)
        sWe[i >> 6][i & 63] = LDF(p_wemb, i, flag);
    __syncthreads();

    // emb for this block's 8 rows; write LDS (for gi) + ws (for chain Phase C)
    #pragma unroll
    for (int q = 0; q < 4; q++) {
        int o = tid + q * 256;
        int e = o & 127, r = o >> 7;
        float acc = LDF(p_bemb, e, flag);
        #pragma unroll
        for (int d = 0; d < 64; d += 4) {
            f32x4 xv = *(const f32x4*)&sX[r][d];
            f32x4 wv = *(const f32x4*)&sWe[e][d];
            acc += xv[0]*wv[0] + xv[1]*wv[1] + xv[2]*wv[2] + xv[3]*wv[3];
        }
        semT2[r][e] = acc;
        ws[OFF_EMB + (size_t)((t * 64 + b0 + r) * 128) + e] = acc;
    }
    __syncthreads();

    // gi = emb @ Wi^T  (wic2 [g][e] read as dwordx4)
    float acc3[3][8];
    #pragma unroll
    for (int g3 = 0; g3 < 3; g3++)
        #pragma unroll
        for (int r = 0; r < 8; r++) acc3[g3][r] = 0.f;
    const float* w2 = ws + OFF_WIC2;
    #pragma unroll 2
    for (int e0 = 0; e0 < 128; e0 += 4) {
        f32x4 wv0 = *(const f32x4*)(w2 + (size_t)(tid      ) * 128 + e0);
        f32x4 wv1 = *(const f32x4*)(w2 + (size_t)(tid + 256) * 128 + e0);
        f32x4 wv2 = *(const f32x4*)(w2 + (size_t)(tid + 512) * 128 + e0);
        f32x4 h[8];
        #pragma unroll
        for (int r = 0; r < 8; r++) h[r] = *(const f32x4*)&semT2[r][e0];
        #pragma unroll
        for (int r = 0; r < 8; r++)
            #pragma unroll
            for (int c = 0; c < 4; c++) {
                acc3[0][r] += wv0[c] * h[r][c];
                acc3[1][r] += wv1[c] * h[r][c];
                acc3[2][r] += wv2[c] * h[r][c];
            }
    }
    // epilogue: fold bi (+bh for r,z), prescale, scatter to stg
    #pragma unroll
    for (int g3 = 0; g3 < 3; g3++) {
        int g = tid + g3 * 256;
        int cellg = g / 384, gr = g % 384;
        int gate = gr / 128, kh = gr % 128;
        int wvp = kh / 32, tt2 = (kh % 32) / 16, l15p = kh % 16;
        int wq = cellg * 4 + wvp;
        float bias = LDF(cellg ? p_bib : p_bia, gr, flag);
        if (gate < 2) bias += LDF(cellg ? p_bhb : p_bha, gr, flag);
        float sc = (gate < 2) ? -LOG2E : TWOLOG2E;
        #pragma unroll
        for (int r = 0; r < 8; r++) {
            float v = sc * (acc3[g3][r] + bias);
            int lane2 = (r >> 2) * 16 + l15p;
            int slot = gate * 8 + tt2 * 4 + (r & 3);
            stg[(wq * 32 + lane2) * 24 + slot] = f2bf(v);
        }
    }
    __syncthreads();
    const uint4* s4 = (const uint4*)stg;                  // 768 uint4
    uint4* d4 = (uint4*)(gipk + (size_t)(t * 8 + chunk) * 6144);
    for (int i = tid; i < 768; i += 256) d4[i] = s4[i];
}

// ---------------- fused chain kernel ----------------
// 480 WGs (prefix p long-first, chunk of 8), 512 threads, 2 WGs/CU.
// Diet vs R10: prescaled exp2 activations, quad-split GRU (quads 2-3 take
// tt=1 gates via shfl_xor 32), stride-136 16B-aligned LDS, b128 A-frags.

__launch_bounds__(512, 2)
__global__ void chain_kernel(const float* ws, void* outv, const int* flagp,
                             const void* p_bha, const void* p_bhb,
                             const void* p_bb, const void* p_ba,
                             const void* p_bo, const void* p_wo)
{
    const int p = PMIN + (NPOUT - 1) - (int)blockIdx.x / NCHUNK;
    const int chunk = (int)blockIdx.x % NCHUNK;
    const int tid = threadIdx.x;
    const int lane = tid & 63;
    const int w = tid >> 6;
    const int cell = w >> 2;
    const int wv = w & 3;
    const int l15 = lane & 15;
    const int quad = lane >> 4;
    const int tt = quad >> 1;       // 0: quads 0-1, 1: quads 2-3 (GRU split)
    const int rquad = quad & 1;     // row-quad for GRU h rows

    __shared__ __align__(16) short hbf[2][2][16][136];   // [buf][cell][row][m] pi-k
    __shared__ __align__(16) short betbf[2][16][136];    // true-e order
    __shared__ __align__(16) short sWm[4][4][64][8];
    __shared__ float spaLds[2][8];

    const unsigned short* gipk = (const unsigned short*)(ws + OFF_GIPK);
    const unsigned short* wpk  = (const unsigned short*)(ws + OFF_WPK);
    const unsigned short* bpk  = (const unsigned short*)(ws + OFF_BPPK);
    const unsigned short* alk  = (const unsigned short*)(ws + OFF_WALPK);
    const int flag = *flagp;

    {   // stage Wm; zero ALL h and beta buffers (rows 8-15 stay zero forever)
        const int* s2 = (const int*)(ws + OFF_WMPK);
        int* d2 = (int*)&sWm[0][0][0][0];
        for (int i = tid; i < 4096; i += 512) d2[i] = s2[i];
        int* hz = (int*)&hbf[0][0][0][0];
        for (int i = tid; i < 4352; i += 512) hz[i] = 0;
        int* bz = (int*)&betbf[0][0][0];
        for (int i = tid; i < 2176; i += 512) bz[i] = 0;
    }

    // persistent B-fragment registers
    s16x8 wB[6][4];
    #pragma unroll
    for (int nt = 0; nt < 6; nt++)
        #pragma unroll
        for (int kt = 0; kt < 4; kt++)
            wB[nt][kt] = *(const s16x8*)(wpk + (((w * 6 + nt) * 4 + kt) * 64 + lane) * 8);
    s16x8 bBp[4], wAl[4];
    #pragma unroll
    for (int kt = 0; kt < 4; kt++) {
        bBp[kt] = *(const s16x8*)(bpk + ((w * 4 + kt) * 64 + lane) * 8);
        wAl[kt] = *(const s16x8*)(alk + (kt * 64 + lane) * 8);
    }

    // per-lane constants (prescaled)
    const float bhnS = TWOLOG2E *
        LDF(cell ? p_bhb : p_bha, 256 + wv * 32 + tt * 16 + l15, flag);
    const float bbE2 = TWOLOG2E * LDF(p_bb, w * 16 + l15, flag);
    const float bafS = LOG2E * LDF(p_ba, 0, flag);
    const float bof  = LDF(p_bo, 0, flag);

    float h_old[4];                 // this lane's tt-half of h rows
    #pragma unroll
    for (int i = 0; i < 4; i++) h_old[i] = 0.f;
    // union accumulator: w<4 -> [0..3]=gAcc, [4..7]=sl4; w>=4 -> [0..7]=cAcc, [8]=slB
    float accR[9];
    #pragma unroll
    for (int i = 0; i < 9; i++) accR[i] = 0.f;

    __syncthreads();

    for (int it = 0; it <= p + 1; it++) {
        const int j = p - it;
        const int jp = j + 1;
        const bool doGru = (j >= 0);
        const bool doAcc = (it > 0);
        const int cur = it & 1;
        const int nxt = cur ^ 1;
        const int dbuf = it & 1;

        // gi for current j (per-lane tt slice, b64 loads)
        s16x4 giv[3];
        if (doGru) {
            const unsigned short* gp0 =
                gipk + ((((size_t)j * 8 + chunk) * 8 + w) * 32 + (lane & 31)) * 24;
            giv[0] = *(const s16x4*)(gp0 + tt * 4);
            giv[1] = *(const s16x4*)(gp0 + 8 + tt * 4);
            giv[2] = *(const s16x4*)(gp0 + 16 + tt * 4);
        }
        // prefetch x / emb for this iteration's Phase C
        f32x4 xv, em0, em1;
        if (doAcc) {
            if (w < 4) {
                xv = *(const f32x4*)(ws + OFF_XT + ((size_t)jp * 64 + w * 16 + l15) * 64
                                     + chunk * 8 + rquad * 4);
            } else {
                const int row8 = (quad * 4 + (w - 4)) & 7;
                const float* ep = ws + OFF_EMB
                                  + ((size_t)jp * 64 + chunk * 8 + row8) * 128 + l15 * 8;
                em0 = *(const f32x4*)ep;
                em1 = *(const f32x4*)(ep + 4);
            }
        }

        // ---- Phase A: MFMA gates + betapre (+ alpha on w==7) ----
        f32x4 Cg[6], Cbp, Cal;
        #pragma unroll
        for (int nt = 0; nt < 6; nt++) Cg[nt] = (f32x4){0.f,0.f,0.f,0.f};
        Cbp = (f32x4){0.f,0.f,0.f,0.f};
        Cal = (f32x4){0.f,0.f,0.f,0.f};

        #pragma unroll
        for (int kt = 0; kt < 4; kt++) {
            s16x8 aB = *(const s16x8*)&hbf[cur][1][l15][kt * 32 + quad * 8];
            s16x8 aA;
            if (cell == 0 || w == 7) aA = *(const s16x8*)&hbf[cur][0][l15][kt * 32 + quad * 8];
            else aA = aB;
            s16x8 aOwn = cell ? aB : aA;
            #pragma unroll
            for (int nt = 0; nt < 6; nt++)
                Cg[nt] = __builtin_amdgcn_mfma_f32_16x16x32_bf16(aOwn, wB[nt][kt], Cg[nt], 0, 0, 0);
            Cbp = __builtin_amdgcn_mfma_f32_16x16x32_bf16(aB, bBp[kt], Cbp, 0, 0, 0);
            if (w == 7)
                Cal = __builtin_amdgcn_mfma_f32_16x16x32_bf16(aA, wAl[kt], Cal, 0, 0, 0);
        }

        // ---- Phase B ----
        if (w == 7 && l15 == 0 && quad < 2) {   // spa in log2 domain
            #pragma unroll
            for (int reg = 0; reg < 4; reg++)
                spaLds[dbuf][quad * 4 + reg] = fminf(Cal[reg] + bafS, 86.f);
        }
        if (doGru) {   // quad-split GRU: all 64 lanes, each does its tt half
            #pragma unroll
            for (int reg = 0; reg < 4; reg++) {
                float s1 = __shfl_xor(Cg[1][reg], 32);
                float s3 = __shfl_xor(Cg[3][reg], 32);
                float s5 = __shfl_xor(Cg[5][reg], 32);
                float ghr = tt ? s1 : Cg[0][reg];
                float ghz = tt ? s3 : Cg[2][reg];
                float ghn = (tt ? s5 : Cg[4][reg]) + bhnS;
                float gir = bf2f((unsigned short)giv[0][reg]);
                float giz = bf2f((unsigned short)giv[1][reg]);
                float gin = bf2f((unsigned short)giv[2][reg]);
                float rr = sig2(gir + ghr);
                float zz = sig2(giz + ghz);
                float nn = tanh2(gin + rr * ghn);
                float hv2 = (1.f - zz) * nn + zz * h_old[reg];
                h_old[reg] = hv2;
                hbf[nxt][cell][rquad * 4 + reg][wv * 32 + l15 * 2 + tt] = (short)f2bf(hv2);
            }
        }
        if (quad < 2) {   // beta = tanh (prescaled arg)
            #pragma unroll
            for (int reg = 0; reg < 4; reg++) {
                float bv = tanh2(Cbp[reg] + bbE2);
                betbf[dbuf][quad * 4 + reg][w * 16 + l15] = (short)f2bf(bv);
            }
        }

        __syncthreads();   // the ONE barrier

        // ---- Phase C: attention accumulation (scan step it-1) ----
        if (doAcc) {
            if (w < 4) {
                f32x4 ec = (f32x4){0.f,0.f,0.f,0.f};
                #pragma unroll
                for (int kt = 0; kt < 4; kt++) {
                    s16x8 a = *(const s16x8*)&betbf[dbuf][l15][kt * 32 + quad * 8];
                    s16x8 bw = *(const s16x8*)&sWm[w][kt][lane][0];
                    ec = __builtin_amdgcn_mfma_f32_16x16x32_bf16(a, bw, ec, 0, 0, 0);
                }
                #pragma unroll
                for (int reg = 0; reg < 4; reg++) {
                    float we = __builtin_exp2f(spaLds[dbuf][(quad * 4 + reg) & 7]);
                    accR[4 + reg] += we;
                    accR[reg] += we * ec[reg] * xv[reg];
                }
            } else {
                const int row8 = (quad * 4 + (w - 4)) & 7;
                float we = __builtin_exp2f(spaLds[dbuf][row8]);
                accR[8] += we;
                const short* bp2 = &betbf[dbuf][row8][l15 * 8];
                s16x4 blo = *(const s16x4*)bp2;
                s16x4 bhi = *(const s16x4*)(bp2 + 4);
                #pragma unroll
                for (int v = 0; v < 4; v++)
                    accR[v] += we * bf2f((unsigned short)blo[v]) * em0[v];
                #pragma unroll
                for (int v = 0; v < 4; v++)
                    accR[4 + v] += we * bf2f((unsigned short)bhi[v]) * em1[v];
            }
        }
    }

    // ---- epilogue ----
    if (w >= 4) {       // pred = (c . Wo)/sl + bo
        const int row = quad * 4 + (w - 4);
        float wo8[8];
        if (flag) {
            const float* wp = (const float*)p_wo + l15 * 8;
            #pragma unroll
            for (int v = 0; v < 8; v++) wo8[v] = wp[v];
        } else {
            const unsigned short* wp = (const unsigned short*)p_wo + l15 * 8;
            #pragma unroll
            for (int v = 0; v < 8; v++) wo8[v] = bf2f(wp[v]);
        }
        float part = 0.f;
        #pragma unroll
        for (int v = 0; v < 8; v++) part += accR[v] * wo8[v];
        part += __shfl_xor(part, 1);
        part += __shfl_xor(part, 2);
        part += __shfl_xor(part, 4);
        part += __shfl_xor(part, 8);
        if (l15 == 0 && row < 8) {
            int bglob = chunk * 8 + row;
            float pr = part / accR[8] + bof;
            size_t oi = (size_t)bglob * NPOUT + (p - PMIN);
            if (flag) ((float*)outv)[oi] = pr;
            else      ((bf16*)outv)[oi] = __float2bfloat16(pr);
        }
    } else if (quad < 2) {   // weight = g/sl/(p+1), rows 0..7
        const float invt = 1.f / (float)(p + 1);
        #pragma unroll
        for (int reg = 0; reg < 4; reg++) {
            int row = quad * 4 + reg;
            int bglob = chunk * 8 + row;
            float gv = accR[reg] / accR[4 + reg] * invt;
            size_t oi = (size_t)B_ * NPOUT
                      + ((size_t)bglob * NPOUT + (p - PMIN)) * 64 + w * 16 + l15;
            if (flag) ((float*)outv)[oi] = gv;
            else      ((bf16*)outv)[oi] = __float2bfloat16(gv);
        }
    }
}

// ---------------- launch ----------------
extern "C" void kernel_launch(void* const* d_in, const int* in_sizes, int n_in,
                              void* d_out, int out_size, void* d_ws, size_t ws_size,
                              hipStream_t stream)
{
    float* ws = (float*)d_ws;
    int* flagp = (int*)(ws + OFF_FLAG);

    hipLaunchKernelGGL(detect_dtype, dim3(1), dim3(256), 0, stream,
                       (const unsigned short*)d_in[0], flagp);
    hipLaunchKernelGGL(prep_all, dim3(1896), dim3(256), 0, stream,
                       d_in[0], d_in[1], d_in[3], d_in[7], d_in[4], d_in[8],
                       d_in[11], d_in[13], d_in[15], ws, flagp);
    hipLaunchKernelGGL(prep_gi, dim3(512), dim3(256), 0, stream,
                       ws, d_in[0], d_in[1], d_in[2], d_in[5], d_in[6],
                       d_in[9], d_in[10], flagp);
    hipLaunchKernelGGL(chain_kernel, dim3(NPOUT * NCHUNK), dim3(512), 0, stream,
                       ws, d_out, flagp,
                       d_in[6], d_in[10], d_in[14], d_in[12], d_in[16], d_in[15]);
}